// Round 10
// baseline (1249.038 us; speedup 1.0000x reference)
//
#include <hip/hip_runtime.h>
#include <math.h>

#define NN 50000
#define NE 800000
#define INF 512
#define HID 64
#define OUTF 40
#define NL 16

// bucketed CSR build parameters
#define NBLK 256      // edge-blocks; NE = NBLK * EPB exactly
#define EPB 3125
#define NBUK 196      // node buckets of 256 (node >> 8); 196*256 = 50176 >= NN
#define SLEN (NBUK * NBLK)  // 50176 count/offset entries per direction

// layer tile
#define TN 32         // nodes per k_layer block
#define FP 72         // LDS row pitch in bf16 (144 B, 16B-aligned)
#define TNP 33        // fp32 accumulator pitch (nodes + 1 pad)

using short8 = __attribute__((ext_vector_type(8))) short;
using f32x4v = __attribute__((ext_vector_type(4))) float;

// bf16 helpers: RNE pack, cheap unpack
__device__ __forceinline__ unsigned int f2bf(float f) {
    unsigned int u = __float_as_uint(f);
    return (u + 0x7fffu + ((u >> 16) & 1u)) >> 16;
}
__device__ __forceinline__ float bflo(unsigned int w) { return __uint_as_float(w << 16); }
__device__ __forceinline__ float bfhi(unsigned int w) { return __uint_as_float(w & 0xffff0000u); }
__device__ __forceinline__ float bfs(unsigned short u) { return __uint_as_float(((unsigned)u) << 16); }

// ---------------- bucketed CSR build (no global atomics) ----------------

// per-(bucket, edge-block) counts; dst counts in cnt2[0..SLEN), src counts in cnt2[SLEN..2*SLEN)
__global__ __launch_bounds__(256) void k_cnt(const int* __restrict__ src, const int* __restrict__ dst,
                                             int* __restrict__ cnt2) {
    __shared__ int hD[NBUK];
    __shared__ int hS[NBUK];
    int t = threadIdx.x;
    int blk = blockIdx.x;
    if (t < NBUK) { hD[t] = 0; hS[t] = 0; }
    __syncthreads();
    int s0 = blk * EPB;
    for (int i = t; i < EPB; i += 256) {
        int e = s0 + i;
        atomicAdd(&hD[dst[e] >> 8], 1);
        atomicAdd(&hS[src[e] >> 8], 1);
    }
    __syncthreads();
    if (t < NBUK) {
        cnt2[t * NBLK + blk] = hD[t];
        cnt2[SLEN + t * NBLK + blk] = hS[t];
    }
}

// scan trio over the CONCATENATED 2*SLEN array (one chain instead of two)
__global__ __launch_bounds__(256) void gscanA(const int* __restrict__ in, int* __restrict__ incl,
                                              int* __restrict__ bsum, int len) {
    __shared__ int lds[256];
    int i = blockIdx.x * 256 + threadIdx.x;
    int v = (i < len) ? in[i] : 0;
    lds[threadIdx.x] = v;
    __syncthreads();
    for (int off = 1; off < 256; off <<= 1) {
        int t = (threadIdx.x >= off) ? lds[threadIdx.x - off] : 0;
        __syncthreads();
        lds[threadIdx.x] += t;
        __syncthreads();
    }
    if (i < len) incl[i] = lds[threadIdx.x];
    if (threadIdx.x == 255) bsum[blockIdx.x] = lds[255];
}

__global__ __launch_bounds__(512) void gscanB(int* __restrict__ bsum, int nb) {
    __shared__ int lds[512];
    int v = (threadIdx.x < nb) ? bsum[threadIdx.x] : 0;
    lds[threadIdx.x] = v;
    __syncthreads();
    for (int off = 1; off < 512; off <<= 1) {
        int t = (threadIdx.x >= off) ? lds[threadIdx.x - off] : 0;
        __syncthreads();
        lds[threadIdx.x] += t;
        __syncthreads();
    }
    if (threadIdx.x < nb) bsum[threadIdx.x] = lds[threadIdx.x] - v;  // exclusive
}

// exclusive offsets; second half (src direction) rebased by -NE (sum of all dst counts)
__global__ __launch_bounds__(256) void gscanC(const int* __restrict__ incl, const int* __restrict__ in,
                                              const int* __restrict__ bsum, int* __restrict__ off, int len) {
    int i = blockIdx.x * 256 + threadIdx.x;
    if (i < len) off[i] = incl[i] - in[i] + bsum[i >> 8] - ((i >= SLEN) ? NE : 0);
}

__global__ __launch_bounds__(256) void k_scat(const int* __restrict__ src, const int* __restrict__ dst,
                                              const int* __restrict__ offD, const int* __restrict__ offS,
                                              uint2* __restrict__ edst, int* __restrict__ esrc) {
    __shared__ int cD[NBUK];
    __shared__ int cS[NBUK];
    int t = threadIdx.x;
    int blk = blockIdx.x;
    if (t < NBUK) { cD[t] = 0; cS[t] = 0; }
    __syncthreads();
    int s0 = blk * EPB;
    for (int i = t; i < EPB; i += 256) {
        int e = s0 + i;
        int d = dst[e];
        int s = src[e];
        int bD = d >> 8;
        int r = atomicAdd(&cD[bD], 1);
        uint2 v;
        v.x = (unsigned)d;
        v.y = (unsigned)s;
        edst[offD[bD * NBLK + blk] + r] = v;
        int bS = s >> 8;
        int r2 = atomicAdd(&cS[bS], 1);
        esrc[offS[bS * NBLK + blk] + r2] = s;
    }
}

// merged: blocks [0,NBUK) build dst-side CSR (nd, row_start, epk); blocks [NBUK,2*NBUK) build ns.
// epk[p] = (src << 5) | (dst & 31): CSR-ordered edges with dst-local id (32-node layer tiles).
__global__ __launch_bounds__(256) void k_build(const uint2* __restrict__ edst, const int* __restrict__ esrc,
                                               const int* __restrict__ offD, const int* __restrict__ offS,
                                               float* __restrict__ nd, int* __restrict__ row_start,
                                               int* __restrict__ epk, float* __restrict__ ns) {
    __shared__ int cnt[256];
    __shared__ int ex[256];
    __shared__ int cur[256];
    int t = threadIdx.x;
    if (blockIdx.x < NBUK) {
        int b = blockIdx.x;
        int base = offD[b * NBLK];
        int end = (b < NBUK - 1) ? offD[(b + 1) * NBLK] : NE;
        cnt[t] = 0;
        __syncthreads();
        for (int p = base + t; p < end; p += 256) {
            uint2 ed = edst[p];
            atomicAdd(&cnt[ed.x & 255], 1);
        }
        __syncthreads();
        int v = cnt[t];
        ex[t] = v;
        __syncthreads();
        for (int off = 1; off < 256; off <<= 1) {
            int tv = (t >= off) ? ex[t - off] : 0;
            __syncthreads();
            ex[t] += tv;
            __syncthreads();
        }
        int excl = ex[t] - v;
        cur[t] = excl;
        int node = b * 256 + t;
        if (node < NN) {
            nd[node] = 1.0f / sqrtf((float)max(v, 1));
            row_start[node] = base + excl;
        }
        __syncthreads();
        for (int p = base + t; p < end; p += 256) {
            uint2 ed = edst[p];
            int r = atomicAdd(&cur[ed.x & 255], 1);
            epk[base + r] = (int)((ed.y << 5) | (ed.x & 31u));
        }
    } else {
        int b = blockIdx.x - NBUK;
        int base = offS[b * NBLK];
        int end = (b < NBUK - 1) ? offS[(b + 1) * NBLK] : NE;
        cnt[t] = 0;
        __syncthreads();
        for (int p = base + t; p < end; p += 256) {
            atomicAdd(&cnt[esrc[p] & 255], 1);
        }
        __syncthreads();
        int node = b * 256 + t;
        if (node < NN) ns[node] = 1.0f / sqrtf((float)max(cnt[t], 1));
    }
}

// ---------------- weight prep (merged): layer weights + Win fragments ----------------
__global__ __launch_bounds__(256) void k_wpp(const float* __restrict__ W1, const float* __restrict__ W2,
                                             const float* __restrict__ Win,
                                             unsigned short* __restrict__ wc, unsigned short* __restrict__ wf) {
    int o = blockIdx.x * 256 + threadIdx.x;
    const int NWC = NL * 4 * 4 * 64 * 8;  // 131072
    if (o < NWC) {
        int j = o & 7;
        int ln = (o >> 3) & 63;
        int c = (o >> 9) & 3;
        int s = (o >> 11) & 3;
        int l = o >> 13;
        int colg = c * 16 + (ln & 15);
        int k = (s & 1) * 32 + ((ln >> 4) << 3) + j;
        float beta = logf(0.5f / (float)(l + 1) + 1.0f);
        const float* W = (s < 2) ? W1 : W2;
        wc[o] = (unsigned short)f2bf(beta * W[((size_t)l * 64 + k) * 64 + colg]);
    } else if (o < NWC + 16 * 4 * 64 * 8) {
        int o2 = o - NWC;
        int jj = o2 & 7;
        int l = (o2 >> 3) & 63;
        int c = (o2 >> 9) & 3;
        int s = o2 >> 11;
        int colg = c * 16 + (l & 15);
        int k = s * 32 + ((l >> 4) << 3) + jj;
        wf[o2] = (unsigned short)f2bf(Win[k * HID + colg]);
    }
}

// ---------------- h0 GEMM: bf16 MFMA (16x16x32), fragment-ordered LDS, K-split x2 ----------------
__global__ __launch_bounds__(256) void k_gemm0(const float* __restrict__ feat, const unsigned short* __restrict__ wf,
                                               float* __restrict__ p0, float* __restrict__ p1) {
    __shared__ unsigned int fS[2048];  // 8 KB: [s(2)][w(4)][lane(64)][4 uints = 8 bf16]
    int tid = threadIdx.x;
    int lane = tid & 63;
    int wv = tid >> 6;
    int bx = blockIdx.x;
    int w = bx >> 1;
    int kh = bx & 1;
    int nb = w * 64;
    f32x4v acc[4];
#pragma unroll
    for (int c = 0; c < 4; c++) acc[c] = {0.0f, 0.0f, 0.0f, 0.0f};

    int k0 = kh * 256;
    for (int kc = k0; kc < k0 + 256; kc += 64) {
        if (kc != k0) __syncthreads();
        float4 t[4];
#pragma unroll
        for (int j = 0; j < 4; j++) {
            int i = tid + j * 256;
            int nl = i >> 4;
            int k4 = i & 15;
            int n = min(nb + nl, NN - 1);
            t[j] = *(const float4*)(feat + (size_t)n * INF + kc + k4 * 4);
        }
#pragma unroll
        for (int j = 0; j < 4; j++) {
            int i = tid + j * 256;
            int nl = i >> 4;
            int kl = (i & 15) * 4;
            int s = kl >> 5;
            int kk = kl & 31;
            int lslot = (nl & 15) | ((kk >> 3) << 4);
            int dstu = (((s * 4 + (nl >> 4)) * 64 + lslot) << 2) + ((kk & 4) >> 1);
            fS[dstu] = f2bf(t[j].x) | (f2bf(t[j].y) << 16);
            fS[dstu + 1] = f2bf(t[j].z) | (f2bf(t[j].w) << 16);
        }
        __syncthreads();
#pragma unroll
        for (int s = 0; s < 2; ++s) {
            int sg = (kc + s * 32) >> 5;
            short8 af = *(const short8*)&fS[((s * 4 + wv) * 64 + lane) << 2];
            short8 bf[4];
#pragma unroll
            for (int c = 0; c < 4; ++c)
                bf[c] = *(const short8*)(wf + ((size_t)(sg * 4 + c) * 64 + lane) * 8);
#pragma unroll
            for (int c = 0; c < 4; ++c)
                acc[c] = __builtin_amdgcn_mfma_f32_16x16x32_bf16(af, bf[c], acc[c], 0, 0, 0);
        }
    }
    float* p = kh ? p1 : p0;
    int nodeb = nb + (wv << 4) + ((lane >> 4) << 2);
    int colb = lane & 15;
#pragma unroll
    for (int r = 0; r < 4; ++r) {
        int node = nodeb + r;
        if (node < NN) {
            float* pp = p + (size_t)node * HID + colb;
#pragma unroll
            for (int c = 0; c < 4; ++c) pp[c * 16] = acc[c][r];
        }
    }
}

// combine: p0+p1, +bias, relu, ns-scale, bf16 pack -> hs, f0b
__global__ __launch_bounds__(256) void k_gfin(const float* __restrict__ p0, const float* __restrict__ p1,
                                              const float* __restrict__ bin, const float* __restrict__ ns,
                                              unsigned int* __restrict__ hs, unsigned int* __restrict__ f0b) {
    int i = blockIdx.x * 256 + threadIdx.x;
    if (i >= NN * 16) return;
    int node = i >> 4;
    int q = i & 15;
    float4 a = ((const float4*)p0)[i];
    float4 b = ((const float4*)p1)[i];
    float4 bi = ((const float4*)bin)[q];
    float nsv = ns[node];
    float q0 = fmaxf(a.x + b.x + bi.x, 0.0f);
    float q1 = fmaxf(a.y + b.y + bi.y, 0.0f);
    float q2 = fmaxf(a.z + b.z + bi.z, 0.0f);
    float q3 = fmaxf(a.w + b.w + bi.w, 0.0f);
    uint2 pk;
    pk.x = f2bf(q0 * nsv) | (f2bf(q1 * nsv) << 16);
    pk.y = f2bf(q2 * nsv) | (f2bf(q3 * nsv) << 16);
    *(uint2*)(hs + (size_t)node * 32 + q * 2) = pk;
    uint2 pf;
    pf.x = f2bf(q0 * 0.1f) | (f2bf(q1 * 0.1f) << 16);
    pf.y = f2bf(q2 * 0.1f) | (f2bf(q3 * 0.1f) << 16);
    *(uint2*)(f0b + (size_t)node * 32 + q * 2) = pf;
}

// ---------------- fused layer: balanced edge-window agg + fp32 LDS accum + MFMA matmul ----------------
// 256 threads = 4 waves, 32-node tile. The block's CSR edge range is split into 16 UNIFORM
// contiguous windows (one per 16-lane group) -> no per-node stragglers, no intra-wave divergence.
// Gather: uint4 pair-gather (8 edges/instr, shfl-broadcast epk). dst-sorted windows -> per-half
// register runs; flush to fp32 LDS tile fT32[dim][node] via atomicAdd at dst-change (~2-3/window;
// addresses distinct across lanes -> no same-address pathology). Then scale+pack bf16 -> MFMA.
__global__ __launch_bounds__(256) void k_layer(const unsigned int* __restrict__ hs_in, const int* __restrict__ epk,
                                               const int* __restrict__ row_start,
                                               const float* __restrict__ nd, const unsigned int* __restrict__ f0b,
                                               const unsigned short* __restrict__ wc, const float* __restrict__ bias,
                                               const float* __restrict__ ns, float omb,
                                               float* __restrict__ h, unsigned int* __restrict__ hs_out, int write_h) {
    __shared__ float fT32[HID * TNP];        // fp32 accumulator [dim][node]
    __shared__ unsigned short fS[TN * FP];   // agg f (scaled 0.9*nd), bf16 (MFMA A layout)
    __shared__ unsigned short f0S[TN * FP];  // f0, bf16
    __shared__ unsigned short oS[TN * FP];   // output bounce
    __shared__ float nsS[TN];
    __shared__ float ndS[TN];
    int tid = threadIdx.x;
    int lane = tid & 63;
    int wv = tid >> 6;   // 0..3
    int nb = blockIdx.x * TN;
    int g = lane >> 4;   // group-in-wave 0..3
    int ql = lane & 15;
    int half = ql >> 3;  // 0: even edges, 1: odd edges
    int qb = ql & 7;     // 16B segment: dims [8qb, 8qb+8)

    for (int i = tid; i < HID * TNP; i += 256) fT32[i] = 0.0f;
    // stage f0 tile: thread i -> node i>>3, 16B segment i&7
    {
        int nl = tid >> 3, sg = tid & 7;
        int n = min(nb + nl, NN - 1);
        uint4 v = *(const uint4*)(f0b + (size_t)n * 32 + sg * 4);
        *(uint4*)&f0S[nl * FP + sg * 8] = v;
    }
    if (tid < TN) {
        nsS[tid] = ns[min(nb + tid, NN - 1)];
        ndS[tid] = nd[min(nb + tid, NN - 1)];
    }
    int base = row_start[nb];
    int end = (nb + TN < NN) ? row_start[nb + TN] : NE;
    __syncthreads();

    // balanced-window aggregation
    {
        int gid = wv * 4 + g;            // 0..15
        int E = end - base;
        int len = (E + 15) >> 4;         // window per group
        int g0 = base + gid * len;
        int g1 = min(g0 + len, end);
        float a0 = 0.f, a1 = 0.f, a2 = 0.f, a3 = 0.f, a4 = 0.f, a5 = 0.f, a6 = 0.f, a7 = 0.f;
        int cur = -1;
        int idxv = 0;
        if (g0 < g1) {
            int c0 = min(16, g1 - g0);
            idxv = (ql < c0) ? epk[g0 + ql] : 0;
        }
#define FLUSHRUN()                                                          \
        do {                                                                \
            float* fd = &fT32[(qb * 8) * TNP + cur];                        \
            atomicAdd(fd + 0 * TNP, a0);                                    \
            atomicAdd(fd + 1 * TNP, a1);                                    \
            atomicAdd(fd + 2 * TNP, a2);                                    \
            atomicAdd(fd + 3 * TNP, a3);                                    \
            atomicAdd(fd + 4 * TNP, a4);                                    \
            atomicAdd(fd + 5 * TNP, a5);                                    \
            atomicAdd(fd + 6 * TNP, a6);                                    \
            atomicAdd(fd + 7 * TNP, a7);                                    \
            a0 = a1 = a2 = a3 = a4 = a5 = a6 = a7 = 0.f;                    \
        } while (0)
        for (int c = g0; c < g1; c += 16) {
            int cnt = min(16, g1 - c);
            int nxtc = c + 16;
            int idxn = 0;
            if (nxtc < g1 && ql < g1 - nxtc) idxn = epk[nxtc + ql];
            unsigned ue[4];
            uint4 pv[4];
#define GATHER4(OFF)                                                        \
            _Pragma("unroll")                                               \
            for (int e = 0; e < 4; ++e) {                                   \
                int ec = (OFF) + 2 * e + half;                              \
                unsigned u = (unsigned)__shfl(idxv, (g << 4) | ec, 64);     \
                ue[e] = u;                                                  \
                uint4 v = {0u, 0u, 0u, 0u};                                 \
                if (ec < cnt) v = *(const uint4*)(hs_in + (size_t)(u >> 5) * 32 + qb * 4); \
                pv[e] = v;                                                  \
            }
#define ACCUM4(OFF)                                                         \
            _Pragma("unroll")                                               \
            for (int e = 0; e < 4; ++e) {                                   \
                int ec = (OFF) + 2 * e + half;                              \
                if (ec < cnt) {                                             \
                    int dl = (int)(ue[e] & 31u);                            \
                    if (dl != cur) {                                        \
                        if (cur >= 0) FLUSHRUN();                           \
                        cur = dl;                                           \
                    }                                                       \
                    a0 += bflo(pv[e].x); a1 += bfhi(pv[e].x);               \
                    a2 += bflo(pv[e].y); a3 += bfhi(pv[e].y);               \
                    a4 += bflo(pv[e].z); a5 += bfhi(pv[e].z);               \
                    a6 += bflo(pv[e].w); a7 += bfhi(pv[e].w);               \
                }                                                           \
            }
            GATHER4(0)
            ACCUM4(0)
            GATHER4(8)
            ACCUM4(8)
#undef GATHER4
#undef ACCUM4
            idxv = idxn;
        }
        if (cur >= 0) FLUSHRUN();
#undef FLUSHRUN
    }
    __syncthreads();

    // scale by 0.9*nd and pack fp32 -> bf16 MFMA A-tile fS[node][dim]
    for (int i = tid; i < HID * TN; i += 256) {
        int d = i >> 5;
        int nl = i & 31;
        float v = fT32[d * TNP + nl] * (0.9f * ndS[nl]);
        fS[nl * FP + d] = (unsigned short)f2bf(v);
    }
    __syncthreads();

    // MFMA: wave wv owns col-tile wv; m-tiles = node halves; K=128 = 4 steps ([f;f0] x [W1;W2])
    int hi = lane >> 4;
    int lo = lane & 15;
    f32x4v acc0 = {0.0f, 0.0f, 0.0f, 0.0f};
    f32x4v acc1 = {0.0f, 0.0f, 0.0f, 0.0f};
#pragma unroll
    for (int s = 0; s < 4; ++s) {
        short8 bf = *(const short8*)(wc + ((size_t)(s * 4 + wv) * 64 + lane) * 8);
        const unsigned short* ab = (s < 2) ? fS : f0S;
        int ko = (s & 1) * 32;
        short8 a0 = *(const short8*)&ab[(0 * 16 + lo) * FP + ko + hi * 8];
        short8 a1 = *(const short8*)&ab[(1 * 16 + lo) * FP + ko + hi * 8];
        acc0 = __builtin_amdgcn_mfma_f32_16x16x32_bf16(a0, bf, acc0, 0, 0, 0);
        acc1 = __builtin_amdgcn_mfma_f32_16x16x32_bf16(a1, bf, acc1, 0, 0, 0);
    }

    // epilogue: + (1-beta)(f+f0) + bias, relu; oS = bf16(q*ns); optional h write (fp32)
    int colg = wv * 16 + lo;
    float bv = bias[colg];
#pragma unroll
    for (int m = 0; m < 2; ++m) {
        f32x4v a = m ? acc1 : acc0;
#pragma unroll
        for (int r = 0; r < 4; ++r) {
            int rowl = m * 16 + hi * 4 + r;
            float fv = bfs(fS[rowl * FP + colg]);
            float f0v = bfs(f0S[rowl * FP + colg]);
            float q = fmaxf(a[r] + omb * (fv + f0v) + bv, 0.0f);
            oS[rowl * FP + colg] = (unsigned short)f2bf(q * nsS[rowl]);
            if (write_h) {
                int node = nb + rowl;
                if (node < NN) h[(size_t)node * HID + colg] = q;
            }
        }
    }
    __syncthreads();

    // coalesced hs_out write: thread i -> node i>>3, 16B segment i&7
    {
        int nl = tid >> 3, sg = tid & 7;
        int node = nb + nl;
        if (node < NN) {
            uint4 v = *(const uint4*)&oS[nl * FP + sg * 8];
            *(uint4*)(hs_out + (size_t)node * 32 + sg * 4) = v;
        }
    }
}

// ---------------- output: block = 128 nodes; wave pair splits the 40 cols; LDS lse reduce ----------------
__global__ __launch_bounds__(256) void k_out(const float* __restrict__ h, const float* __restrict__ Wout,
                                             const float* __restrict__ bout, float* __restrict__ out) {
    __shared__ float red_mx[4][64];
    __shared__ float red_s[4][64];
    int tid = threadIdx.x;
    int lane = tid & 63;
    int wv = tid >> 6;
    int half = wv & 1;
    int grp = wv >> 1;
    int node = blockIdx.x * 128 + grp * 64 + lane;
    int nodec = min(node, NN - 1);
    float acc[20];
#pragma unroll
    for (int c = 0; c < 20; c++) acc[c] = 0.0f;
    const float4* hr = (const float4*)(h + (size_t)nodec * HID);
    const float* wb = Wout + half * 20;
    for (int kk = 0; kk < HID / 4; ++kk) {
        float4 a = hr[kk];
        float av[4] = {a.x, a.y, a.z, a.w};
#pragma unroll
        for (int j = 0; j < 4; j++) {
            const float* wr = wb + (size_t)(kk * 4 + j) * OUTF;
#pragma unroll
            for (int c = 0; c < 20; c++) acc[c] += av[j] * wr[c];
        }
    }
    const float* bp = bout + half * 20;
#pragma unroll
    for (int c = 0; c < 20; c++) acc[c] += bp[c];
    float mx = acc[0];
#pragma unroll
    for (int c = 1; c < 20; c++) mx = fmaxf(mx, acc[c]);
    red_mx[wv][lane] = mx;
    __syncthreads();
    float gmx = fmaxf(mx, red_mx[wv ^ 1][lane]);
    float s = 0.0f;
#pragma unroll
    for (int c = 0; c < 20; c++) s += expf(acc[c] - gmx);
    red_s[wv][lane] = s;
    __syncthreads();
    float lse = logf(s + red_s[wv ^ 1][lane]) + gmx;
    if (node < NN) {
        float4* op = (float4*)(out + (size_t)node * OUTF + half * 20);
#pragma unroll
        for (int q = 0; q < 5; q++) {
            float4 v;
            v.x = acc[q * 4 + 0] - lse;
            v.y = acc[q * 4 + 1] - lse;
            v.z = acc[q * 4 + 2] - lse;
            v.w = acc[q * 4 + 3] - lse;
            op[q] = v;
        }
    }
}

extern "C" void kernel_launch(void* const* d_in, const int* in_sizes, int n_in,
                              void* d_out, int out_size, void* d_ws, size_t ws_size,
                              hipStream_t stream) {
    const float* feat = (const float*)d_in[0];
    const float* Win  = (const float*)d_in[1];
    const float* bin  = (const float*)d_in[2];
    const float* W1   = (const float*)d_in[3];
    const float* W2   = (const float*)d_in[4];
    const float* bvec = (const float*)d_in[5];
    const float* Wout = (const float*)d_in[6];
    const float* bout = (const float*)d_in[7];
    const int*   src  = (const int*)d_in[8];
    const int*   dst  = (const int*)d_in[9];
    float* out = (float*)d_out;

    char* ws = (char*)d_ws;
    size_t off = 0;
    auto take = [&](size_t bytes) {
        void* p = ws + off;
        off += (bytes + 255) & ~(size_t)255;
        return p;
    };
    int* bsum      = (int*)take(512 * 4);
    int* row_start = (int*)take(NN * 4);
    int* epk       = (int*)take(NE * 4);
    float* nsrc    = (float*)take(NN * 4);
    float* ndst    = (float*)take(NN * 4);
    int* cnt2      = (int*)take(2 * SLEN * 4);   // [cntD | cntS]
    int* off2      = (int*)take(2 * SLEN * 4);   // [offD | offS]
    int* sincl     = (int*)take(2 * SLEN * 4);
    unsigned short* wcat  = (unsigned short*)take((size_t)NL * 4 * 4 * 64 * 8 * 2);  // 256 KB bf16 frags
    unsigned short* wfrag = (unsigned short*)take((size_t)INF * HID * 2);
    unsigned int* f0b = (unsigned int*)take((size_t)NN * HID * 2);  // bf16
    float* hbuf    = (float*)take((size_t)NN * HID * 4);            // gemm0 partial p0; edst alias; h
    float* part1   = (float*)take((size_t)NN * HID * 4);            // gemm0 partial p1; esrc alias
    unsigned int* hsA = (unsigned int*)take((size_t)NN * HID * 2);  // bf16
    unsigned int* hsB = (unsigned int*)take((size_t)NN * HID * 2);  // bf16

    // setup-phase aliases (dead before k_gemm0 writes them)
    uint2* edst = (uint2*)hbuf;   // NE * 8B = 6.4 MB <= 12.8 MB
    int* esrc   = (int*)part1;    // NE * 4B = 3.2 MB
    int* offD = off2;
    int* offS = off2 + SLEN;

    const int NB_W = (NN + 63) / 64;     // 782
    const int NB_L = (NN + TN - 1) / TN; // 1563
    const int NB_O = (NN + 127) / 128;   // 391
    const int NB_S2 = 2 * SLEN / 256;    // 392

    // bucketed CSR build (zero global atomics), single concatenated scan chain
    k_cnt<<<NBLK, 256, 0, stream>>>(src, dst, cnt2);
    gscanA<<<NB_S2, 256, 0, stream>>>(cnt2, sincl, bsum, 2 * SLEN);
    gscanB<<<1, 512, 0, stream>>>(bsum, NB_S2);
    gscanC<<<NB_S2, 256, 0, stream>>>(sincl, cnt2, bsum, off2, 2 * SLEN);
    k_scat<<<NBLK, 256, 0, stream>>>(src, dst, offD, offS, edst, esrc);
    k_build<<<2 * NBUK, 256, 0, stream>>>(edst, esrc, offD, offS, ndst, row_start, epk, nsrc);

    k_wpp<<<(NL * 4 * 4 * 64 * 8 + INF * HID + 255) / 256, 256, 0, stream>>>(W1, W2, Win, wcat, wfrag);
    k_gemm0<<<2 * NB_W, 256, 0, stream>>>(feat, wfrag, hbuf, part1);
    k_gfin<<<(NN * 16 + 255) / 256, 256, 0, stream>>>(hbuf, part1, bin, nsrc, hsA, f0b);

    // ping-pong bf16 hs buffers (gathers read arbitrary rows; in-place would race)
    for (int l = 0; l < NL; ++l) {
        const unsigned int* hin = (l & 1) ? hsB : hsA;
        unsigned int* hout = (l & 1) ? hsA : hsB;
        float beta = logf(0.5f / (float)(l + 1) + 1.0f);
        float omb = 1.0f - beta;
        k_layer<<<NB_L, 256, 0, stream>>>(hin, epk, row_start, ndst, f0b,
                                          wcat + (size_t)l * 4 * 4 * 64 * 8, bvec + l * HID,
                                          nsrc, omb, hbuf, hout, (l == NL - 1) ? 1 : 0);
    }
    k_out<<<NB_O, 256, 0, stream>>>(hbuf, Wout, bout, out);
}

// Round 11
// 556.994 us; speedup vs baseline: 2.2425x; 2.2425x over previous
//
#include <hip/hip_runtime.h>
#include <math.h>

#define NN 50000
#define NE 800000
#define INF 512
#define HID 64
#define OUTF 40
#define NL 16

// bucketed CSR build parameters
#define NBLK 256      // edge-blocks; NE = NBLK * EPB exactly
#define EPB 3125
#define NBUK 196      // node buckets of 256 (node >> 8); 196*256 = 50176 >= NN
#define SLEN (NBUK * NBLK)  // 50176 count/offset entries per direction

// layer tile
#define TN 32         // nodes per k_layer block
#define FP 72         // LDS row pitch in bf16 (144 B, 16B-aligned)

using short8 = __attribute__((ext_vector_type(8))) short;
using f32x4v = __attribute__((ext_vector_type(4))) float;

// bf16 helpers: RNE pack, cheap unpack
__device__ __forceinline__ unsigned int f2bf(float f) {
    unsigned int u = __float_as_uint(f);
    return (u + 0x7fffu + ((u >> 16) & 1u)) >> 16;
}
__device__ __forceinline__ float bflo(unsigned int w) { return __uint_as_float(w << 16); }
__device__ __forceinline__ float bfhi(unsigned int w) { return __uint_as_float(w & 0xffff0000u); }
__device__ __forceinline__ float bfs(unsigned short u) { return __uint_as_float(((unsigned)u) << 16); }

// ---------------- bucketed CSR build (no global atomics) ----------------

// per-(bucket, edge-block) counts; dst counts in cnt2[0..SLEN), src counts in cnt2[SLEN..2*SLEN)
__global__ __launch_bounds__(256) void k_cnt(const int* __restrict__ src, const int* __restrict__ dst,
                                             int* __restrict__ cnt2) {
    __shared__ int hD[NBUK];
    __shared__ int hS[NBUK];
    int t = threadIdx.x;
    int blk = blockIdx.x;
    if (t < NBUK) { hD[t] = 0; hS[t] = 0; }
    __syncthreads();
    int s0 = blk * EPB;
    for (int i = t; i < EPB; i += 256) {
        int e = s0 + i;
        atomicAdd(&hD[dst[e] >> 8], 1);
        atomicAdd(&hS[src[e] >> 8], 1);
    }
    __syncthreads();
    if (t < NBUK) {
        cnt2[t * NBLK + blk] = hD[t];
        cnt2[SLEN + t * NBLK + blk] = hS[t];
    }
}

// scan trio over the CONCATENATED 2*SLEN array (one chain instead of two)
__global__ __launch_bounds__(256) void gscanA(const int* __restrict__ in, int* __restrict__ incl,
                                              int* __restrict__ bsum, int len) {
    __shared__ int lds[256];
    int i = blockIdx.x * 256 + threadIdx.x;
    int v = (i < len) ? in[i] : 0;
    lds[threadIdx.x] = v;
    __syncthreads();
    for (int off = 1; off < 256; off <<= 1) {
        int t = (threadIdx.x >= off) ? lds[threadIdx.x - off] : 0;
        __syncthreads();
        lds[threadIdx.x] += t;
        __syncthreads();
    }
    if (i < len) incl[i] = lds[threadIdx.x];
    if (threadIdx.x == 255) bsum[blockIdx.x] = lds[255];
}

__global__ __launch_bounds__(512) void gscanB(int* __restrict__ bsum, int nb) {
    __shared__ int lds[512];
    int v = (threadIdx.x < nb) ? bsum[threadIdx.x] : 0;
    lds[threadIdx.x] = v;
    __syncthreads();
    for (int off = 1; off < 512; off <<= 1) {
        int t = (threadIdx.x >= off) ? lds[threadIdx.x - off] : 0;
        __syncthreads();
        lds[threadIdx.x] += t;
        __syncthreads();
    }
    if (threadIdx.x < nb) bsum[threadIdx.x] = lds[threadIdx.x] - v;  // exclusive
}

// exclusive offsets; second half (src direction) rebased by -NE (sum of all dst counts)
__global__ __launch_bounds__(256) void gscanC(const int* __restrict__ incl, const int* __restrict__ in,
                                              const int* __restrict__ bsum, int* __restrict__ off, int len) {
    int i = blockIdx.x * 256 + threadIdx.x;
    if (i < len) off[i] = incl[i] - in[i] + bsum[i >> 8] - ((i >= SLEN) ? NE : 0);
}

__global__ __launch_bounds__(256) void k_scat(const int* __restrict__ src, const int* __restrict__ dst,
                                              const int* __restrict__ offD, const int* __restrict__ offS,
                                              uint2* __restrict__ edst, int* __restrict__ esrc) {
    __shared__ int cD[NBUK];
    __shared__ int cS[NBUK];
    int t = threadIdx.x;
    int blk = blockIdx.x;
    if (t < NBUK) { cD[t] = 0; cS[t] = 0; }
    __syncthreads();
    int s0 = blk * EPB;
    for (int i = t; i < EPB; i += 256) {
        int e = s0 + i;
        int d = dst[e];
        int s = src[e];
        int bD = d >> 8;
        int r = atomicAdd(&cD[bD], 1);
        uint2 v;
        v.x = (unsigned)d;
        v.y = (unsigned)s;
        edst[offD[bD * NBLK + blk] + r] = v;
        int bS = s >> 8;
        int r2 = atomicAdd(&cS[bS], 1);
        esrc[offS[bS * NBLK + blk] + r2] = s;
    }
}

// merged: blocks [0,NBUK) build dst-side CSR (nd, row_start, col); blocks [NBUK,2*NBUK) build ns
__global__ __launch_bounds__(256) void k_build(const uint2* __restrict__ edst, const int* __restrict__ esrc,
                                               const int* __restrict__ offD, const int* __restrict__ offS,
                                               float* __restrict__ nd, int* __restrict__ row_start,
                                               int* __restrict__ col, float* __restrict__ ns) {
    __shared__ int cnt[256];
    __shared__ int ex[256];
    __shared__ int cur[256];
    int t = threadIdx.x;
    if (blockIdx.x < NBUK) {
        int b = blockIdx.x;
        int base = offD[b * NBLK];
        int end = (b < NBUK - 1) ? offD[(b + 1) * NBLK] : NE;
        cnt[t] = 0;
        __syncthreads();
        for (int p = base + t; p < end; p += 256) {
            uint2 ed = edst[p];
            atomicAdd(&cnt[ed.x & 255], 1);
        }
        __syncthreads();
        int v = cnt[t];
        ex[t] = v;
        __syncthreads();
        for (int off = 1; off < 256; off <<= 1) {
            int tv = (t >= off) ? ex[t - off] : 0;
            __syncthreads();
            ex[t] += tv;
            __syncthreads();
        }
        int excl = ex[t] - v;
        cur[t] = excl;
        int node = b * 256 + t;
        if (node < NN) {
            nd[node] = 1.0f / sqrtf((float)max(v, 1));
            row_start[node] = base + excl;
        }
        __syncthreads();
        for (int p = base + t; p < end; p += 256) {
            uint2 ed = edst[p];
            int r = atomicAdd(&cur[ed.x & 255], 1);
            col[base + r] = (int)ed.y;
        }
    } else {
        int b = blockIdx.x - NBUK;
        int base = offS[b * NBLK];
        int end = (b < NBUK - 1) ? offS[(b + 1) * NBLK] : NE;
        cnt[t] = 0;
        __syncthreads();
        for (int p = base + t; p < end; p += 256) {
            atomicAdd(&cnt[esrc[p] & 255], 1);
        }
        __syncthreads();
        int node = b * 256 + t;
        if (node < NN) ns[node] = 1.0f / sqrtf((float)max(cnt[t], 1));
    }
}

// ---------------- weight prep (merged): layer weights + Win fragments ----------------
// wc layout [l][s(4)][c(4)][lane(64)][j(8)], beta-scaled bf16, combined K=128 ([W1;W2]).
// wf layout [s(16)][c(4)][lane(64)][j(8)] for the h0 GEMM.
__global__ __launch_bounds__(256) void k_wpp(const float* __restrict__ W1, const float* __restrict__ W2,
                                             const float* __restrict__ Win,
                                             unsigned short* __restrict__ wc, unsigned short* __restrict__ wf) {
    int o = blockIdx.x * 256 + threadIdx.x;
    const int NWC = NL * 4 * 4 * 64 * 8;  // 131072
    if (o < NWC) {
        int j = o & 7;
        int ln = (o >> 3) & 63;
        int c = (o >> 9) & 3;
        int s = (o >> 11) & 3;
        int l = o >> 13;
        int colg = c * 16 + (ln & 15);
        int k = (s & 1) * 32 + ((ln >> 4) << 3) + j;
        float beta = logf(0.5f / (float)(l + 1) + 1.0f);
        const float* W = (s < 2) ? W1 : W2;
        wc[o] = (unsigned short)f2bf(beta * W[((size_t)l * 64 + k) * 64 + colg]);
    } else if (o < NWC + 16 * 4 * 64 * 8) {
        int o2 = o - NWC;
        int jj = o2 & 7;
        int l = (o2 >> 3) & 63;
        int c = (o2 >> 9) & 3;
        int s = o2 >> 11;
        int colg = c * 16 + (l & 15);
        int k = s * 32 + ((l >> 4) << 3) + jj;
        wf[o2] = (unsigned short)f2bf(Win[k * HID + colg]);
    }
}

// ---------------- h0 GEMM: bf16 MFMA (16x16x32), fragment-ordered LDS, K-split x2 ----------------
__global__ __launch_bounds__(256) void k_gemm0(const float* __restrict__ feat, const unsigned short* __restrict__ wf,
                                               float* __restrict__ p0, float* __restrict__ p1) {
    __shared__ unsigned int fS[2048];  // 8 KB: [s(2)][w(4)][lane(64)][4 uints = 8 bf16]
    int tid = threadIdx.x;
    int lane = tid & 63;
    int wv = tid >> 6;
    int bx = blockIdx.x;
    int w = bx >> 1;
    int kh = bx & 1;
    int nb = w * 64;
    f32x4v acc[4];
#pragma unroll
    for (int c = 0; c < 4; c++) acc[c] = {0.0f, 0.0f, 0.0f, 0.0f};

    int k0 = kh * 256;
    for (int kc = k0; kc < k0 + 256; kc += 64) {
        if (kc != k0) __syncthreads();
        float4 t[4];
#pragma unroll
        for (int j = 0; j < 4; j++) {
            int i = tid + j * 256;
            int nl = i >> 4;
            int k4 = i & 15;
            int n = min(nb + nl, NN - 1);
            t[j] = *(const float4*)(feat + (size_t)n * INF + kc + k4 * 4);
        }
#pragma unroll
        for (int j = 0; j < 4; j++) {
            int i = tid + j * 256;
            int nl = i >> 4;
            int kl = (i & 15) * 4;
            int s = kl >> 5;
            int kk = kl & 31;
            int lslot = (nl & 15) | ((kk >> 3) << 4);
            int dstu = (((s * 4 + (nl >> 4)) * 64 + lslot) << 2) + ((kk & 4) >> 1);
            fS[dstu] = f2bf(t[j].x) | (f2bf(t[j].y) << 16);
            fS[dstu + 1] = f2bf(t[j].z) | (f2bf(t[j].w) << 16);
        }
        __syncthreads();
#pragma unroll
        for (int s = 0; s < 2; ++s) {
            int sg = (kc + s * 32) >> 5;
            short8 af = *(const short8*)&fS[((s * 4 + wv) * 64 + lane) << 2];
            short8 bf[4];
#pragma unroll
            for (int c = 0; c < 4; ++c)
                bf[c] = *(const short8*)(wf + ((size_t)(sg * 4 + c) * 64 + lane) * 8);
#pragma unroll
            for (int c = 0; c < 4; ++c)
                acc[c] = __builtin_amdgcn_mfma_f32_16x16x32_bf16(af, bf[c], acc[c], 0, 0, 0);
        }
    }
    float* p = kh ? p1 : p0;
    int nodeb = nb + (wv << 4) + ((lane >> 4) << 2);
    int colb = lane & 15;
#pragma unroll
    for (int r = 0; r < 4; ++r) {
        int node = nodeb + r;
        if (node < NN) {
            float* pp = p + (size_t)node * HID + colb;
#pragma unroll
            for (int c = 0; c < 4; ++c) pp[c * 16] = acc[c][r];
        }
    }
}

// combine: p0+p1, +bias, relu, ns-scale, bf16 pack -> hs, f0b
__global__ __launch_bounds__(256) void k_gfin(const float* __restrict__ p0, const float* __restrict__ p1,
                                              const float* __restrict__ bin, const float* __restrict__ ns,
                                              unsigned int* __restrict__ hs, unsigned int* __restrict__ f0b) {
    int i = blockIdx.x * 256 + threadIdx.x;
    if (i >= NN * 16) return;
    int node = i >> 4;
    int q = i & 15;
    float4 a = ((const float4*)p0)[i];
    float4 b = ((const float4*)p1)[i];
    float4 bi = ((const float4*)bin)[q];
    float nsv = ns[node];
    float q0 = fmaxf(a.x + b.x + bi.x, 0.0f);
    float q1 = fmaxf(a.y + b.y + bi.y, 0.0f);
    float q2 = fmaxf(a.z + b.z + bi.z, 0.0f);
    float q3 = fmaxf(a.w + b.w + bi.w, 0.0f);
    uint2 pk;
    pk.x = f2bf(q0 * nsv) | (f2bf(q1 * nsv) << 16);
    pk.y = f2bf(q2 * nsv) | (f2bf(q3 * nsv) << 16);
    *(uint2*)(hs + (size_t)node * 32 + q * 2) = pk;
    uint2 pf;
    pf.x = f2bf(q0 * 0.1f) | (f2bf(q1 * 0.1f) << 16);
    pf.y = f2bf(q2 * 0.1f) | (f2bf(q3 * 0.1f) << 16);
    *(uint2*)(f0b + (size_t)node * 32 + q * 2) = pf;
}

// ---------------- fused layer: pair-gather agg (uint4, 8 edges/instr) + MFMA matmul ----------------
// 256 threads = 4 waves, 32-node tile. 16-lane group per node; within a group, lanes ql<8 own the
// EVEN edges' full 128B rows (16B each), lanes ql>=8 the ODD edges' -> one wave-gather covers
// 8 edges. Per-lane fp32 accum of dims [8(ql&7), +8); __shfl_xor(8) merges even/odd partials
// (reassociation only). Then K=128 MFMA + fp32 identity epilogue.
__global__ __launch_bounds__(256) void k_layer(const unsigned int* __restrict__ hs_in, const int* __restrict__ col,
                                               const int* __restrict__ row_start,
                                               const float* __restrict__ nd, const unsigned int* __restrict__ f0b,
                                               const unsigned short* __restrict__ wc, const float* __restrict__ bias,
                                               const float* __restrict__ ns, float omb,
                                               float* __restrict__ h, unsigned int* __restrict__ hs_out, int write_h) {
    __shared__ unsigned short fS[TN * FP];   // agg f (scaled 0.9*nd), bf16
    __shared__ unsigned short f0S[TN * FP];  // f0, bf16
    __shared__ unsigned short oS[TN * FP];   // output bounce
    __shared__ float nsS[TN];
    int tid = threadIdx.x;
    int lane = tid & 63;
    int wv = tid >> 6;   // 0..3
    int nb = blockIdx.x * TN;
    int g = lane >> 4;   // group-in-wave 0..3
    int ql = lane & 15;
    int half = ql >> 3;  // 0: even edges, 1: odd edges
    int qb = ql & 7;     // 16B segment: dims [8qb, 8qb+8)

    // stage f0 tile: thread i -> node i>>3, 16B segment i&7
    {
        int nl = tid >> 3, sg = tid & 7;
        int n = min(nb + nl, NN - 1);
        uint4 v = *(const uint4*)(f0b + (size_t)n * 32 + sg * 4);
        *(uint4*)&f0S[nl * FP + sg * 8] = v;
    }
    if (tid < TN) nsS[tid] = ns[min(nb + tid, NN - 1)];

    // hoist both passes' metadata + first-chunk col indices
    int nlP[2], baseP[2], degP[2], idxP[2];
    float ndP[2];
#pragma unroll
    for (int p = 0; p < 2; ++p) {
        int nl = p * 16 + wv * 4 + g;
        int n = min(nb + nl, NN - 1);
        nlP[p] = nl;
        int base = row_start[n];
        int nxt = (n < NN - 1) ? row_start[n + 1] : NE;
        baseP[p] = base;
        degP[p] = nxt - base;
        ndP[p] = nd[n];
    }
#pragma unroll
    for (int p = 0; p < 2; ++p) {
        idxP[p] = (ql < min(16, degP[p])) ? col[baseP[p] + ql] : 0;
    }

    // pair-gather aggregation
#pragma unroll
    for (int pass = 0; pass < 2; ++pass) {
        int base = baseP[pass];
        int deg = degP[pass];
        int idxv = idxP[pass];
        float a0 = 0.f, a1 = 0.f, a2 = 0.f, a3 = 0.f, a4 = 0.f, a5 = 0.f, a6 = 0.f, a7 = 0.f;
        for (int done = 0; done < deg; done += 16) {
            int cnt = min(16, deg - done);
            int nxt = done + 16;
            int idxn = 0;
            if (nxt < deg && ql < deg - nxt) idxn = col[base + nxt + ql];
            uint4 pv[4];
#pragma unroll
            for (int e = 0; e < 4; ++e) {
                int ec = 2 * e + half;
                int s = __shfl(idxv, (g << 4) | ec, 64);
                uint4 v = {0u, 0u, 0u, 0u};
                if (ec < cnt) v = *(const uint4*)(hs_in + (size_t)s * 32 + qb * 4);
                pv[e] = v;
            }
#pragma unroll
            for (int e = 0; e < 4; ++e) {
                a0 += bflo(pv[e].x); a1 += bfhi(pv[e].x);
                a2 += bflo(pv[e].y); a3 += bfhi(pv[e].y);
                a4 += bflo(pv[e].z); a5 += bfhi(pv[e].z);
                a6 += bflo(pv[e].w); a7 += bfhi(pv[e].w);
            }
#pragma unroll
            for (int e = 0; e < 4; ++e) {
                int ec = 8 + 2 * e + half;
                int s = __shfl(idxv, (g << 4) | ec, 64);
                uint4 v = {0u, 0u, 0u, 0u};
                if (ec < cnt) v = *(const uint4*)(hs_in + (size_t)s * 32 + qb * 4);
                pv[e] = v;
            }
#pragma unroll
            for (int e = 0; e < 4; ++e) {
                a0 += bflo(pv[e].x); a1 += bfhi(pv[e].x);
                a2 += bflo(pv[e].y); a3 += bfhi(pv[e].y);
                a4 += bflo(pv[e].z); a5 += bfhi(pv[e].z);
                a6 += bflo(pv[e].w); a7 += bfhi(pv[e].w);
            }
            idxv = idxn;
        }
        // merge even/odd partials across ql^8 (same dims on both lanes)
        a0 += __shfl_xor(a0, 8, 64);
        a1 += __shfl_xor(a1, 8, 64);
        a2 += __shfl_xor(a2, 8, 64);
        a3 += __shfl_xor(a3, 8, 64);
        a4 += __shfl_xor(a4, 8, 64);
        a5 += __shfl_xor(a5, 8, 64);
        a6 += __shfl_xor(a6, 8, 64);
        a7 += __shfl_xor(a7, 8, 64);
        float sc = 0.9f * ndP[pass];
        int nl = nlP[pass];
        if (half == 0) {
            uint4 w;
            w.x = f2bf(a0 * sc) | (f2bf(a1 * sc) << 16);
            w.y = f2bf(a2 * sc) | (f2bf(a3 * sc) << 16);
            w.z = f2bf(a4 * sc) | (f2bf(a5 * sc) << 16);
            w.w = f2bf(a6 * sc) | (f2bf(a7 * sc) << 16);
            *(uint4*)&fS[nl * FP + qb * 8] = w;
        }
    }
    __syncthreads();

    // MFMA: wave wv owns col-tile wv; m-tiles = node halves; K=128 = 4 steps ([f;f0] x [W1;W2])
    int hi = lane >> 4;
    int lo = lane & 15;
    f32x4v acc0 = {0.0f, 0.0f, 0.0f, 0.0f};
    f32x4v acc1 = {0.0f, 0.0f, 0.0f, 0.0f};
#pragma unroll
    for (int s = 0; s < 4; ++s) {
        short8 bf = *(const short8*)(wc + ((size_t)(s * 4 + wv) * 64 + lane) * 8);
        const unsigned short* ab = (s < 2) ? fS : f0S;
        int ko = (s & 1) * 32;
        short8 a0 = *(const short8*)&ab[(0 * 16 + lo) * FP + ko + hi * 8];
        short8 a1 = *(const short8*)&ab[(1 * 16 + lo) * FP + ko + hi * 8];
        acc0 = __builtin_amdgcn_mfma_f32_16x16x32_bf16(a0, bf, acc0, 0, 0, 0);
        acc1 = __builtin_amdgcn_mfma_f32_16x16x32_bf16(a1, bf, acc1, 0, 0, 0);
    }

    // epilogue: + (1-beta)(f+f0) + bias, relu; oS = bf16(q*ns); optional h write (fp32)
    int colg = wv * 16 + lo;
    float bv = bias[colg];
#pragma unroll
    for (int m = 0; m < 2; ++m) {
        f32x4v a = m ? acc1 : acc0;
#pragma unroll
        for (int r = 0; r < 4; ++r) {
            int rowl = m * 16 + hi * 4 + r;
            float fv = bfs(fS[rowl * FP + colg]);
            float f0v = bfs(f0S[rowl * FP + colg]);
            float q = fmaxf(a[r] + omb * (fv + f0v) + bv, 0.0f);
            oS[rowl * FP + colg] = (unsigned short)f2bf(q * nsS[rowl]);
            if (write_h) {
                int node = nb + rowl;
                if (node < NN) h[(size_t)node * HID + colg] = q;
            }
        }
    }
    __syncthreads();

    // coalesced hs_out write: thread i -> node i>>3, 16B segment i&7
    {
        int nl = tid >> 3, sg = tid & 7;
        int node = nb + nl;
        if (node < NN) {
            uint4 v = *(const uint4*)&oS[nl * FP + sg * 8];
            *(uint4*)(hs_out + (size_t)node * 32 + sg * 4) = v;
        }
    }
}

// ---------------- output: block = 128 nodes; wave pair splits the 40 cols; LDS lse reduce ----------------
__global__ __launch_bounds__(256) void k_out(const float* __restrict__ h, const float* __restrict__ Wout,
                                             const float* __restrict__ bout, float* __restrict__ out) {
    __shared__ float red_mx[4][64];
    __shared__ float red_s[4][64];
    int tid = threadIdx.x;
    int lane = tid & 63;
    int wv = tid >> 6;
    int half = wv & 1;
    int grp = wv >> 1;
    int node = blockIdx.x * 128 + grp * 64 + lane;
    int nodec = min(node, NN - 1);
    float acc[20];
#pragma unroll
    for (int c = 0; c < 20; c++) acc[c] = 0.0f;
    const float4* hr = (const float4*)(h + (size_t)nodec * HID);
    const float* wb = Wout + half * 20;
    for (int kk = 0; kk < HID / 4; ++kk) {
        float4 a = hr[kk];
        float av[4] = {a.x, a.y, a.z, a.w};
#pragma unroll
        for (int j = 0; j < 4; j++) {
            const float* wr = wb + (size_t)(kk * 4 + j) * OUTF;
#pragma unroll
            for (int c = 0; c < 20; c++) acc[c] += av[j] * wr[c];
        }
    }
    const float* bp = bout + half * 20;
#pragma unroll
    for (int c = 0; c < 20; c++) acc[c] += bp[c];
    float mx = acc[0];
#pragma unroll
    for (int c = 1; c < 20; c++) mx = fmaxf(mx, acc[c]);
    red_mx[wv][lane] = mx;
    __syncthreads();
    float gmx = fmaxf(mx, red_mx[wv ^ 1][lane]);
    float s = 0.0f;
#pragma unroll
    for (int c = 0; c < 20; c++) s += expf(acc[c] - gmx);
    red_s[wv][lane] = s;
    __syncthreads();
    float lse = logf(s + red_s[wv ^ 1][lane]) + gmx;
    if (node < NN) {
        float4* op = (float4*)(out + (size_t)node * OUTF + half * 20);
#pragma unroll
        for (int q = 0; q < 5; q++) {
            float4 v;
            v.x = acc[q * 4 + 0] - lse;
            v.y = acc[q * 4 + 1] - lse;
            v.z = acc[q * 4 + 2] - lse;
            v.w = acc[q * 4 + 3] - lse;
            op[q] = v;
        }
    }
}

extern "C" void kernel_launch(void* const* d_in, const int* in_sizes, int n_in,
                              void* d_out, int out_size, void* d_ws, size_t ws_size,
                              hipStream_t stream) {
    const float* feat = (const float*)d_in[0];
    const float* Win  = (const float*)d_in[1];
    const float* bin  = (const float*)d_in[2];
    const float* W1   = (const float*)d_in[3];
    const float* W2   = (const float*)d_in[4];
    const float* bvec = (const float*)d_in[5];
    const float* Wout = (const float*)d_in[6];
    const float* bout = (const float*)d_in[7];
    const int*   src  = (const int*)d_in[8];
    const int*   dst  = (const int*)d_in[9];
    float* out = (float*)d_out;

    char* ws = (char*)d_ws;
    size_t off = 0;
    auto take = [&](size_t bytes) {
        void* p = ws + off;
        off += (bytes + 255) & ~(size_t)255;
        return p;
    };
    int* bsum      = (int*)take(512 * 4);
    int* row_start = (int*)take(NN * 4);
    int* col       = (int*)take(NE * 4);
    float* nsrc    = (float*)take(NN * 4);
    float* ndst    = (float*)take(NN * 4);
    int* cnt2      = (int*)take(2 * SLEN * 4);   // [cntD | cntS]
    int* off2      = (int*)take(2 * SLEN * 4);   // [offD | offS]
    int* sincl     = (int*)take(2 * SLEN * 4);
    unsigned short* wcat  = (unsigned short*)take((size_t)NL * 4 * 4 * 64 * 8 * 2);  // 256 KB bf16 frags
    unsigned short* wfrag = (unsigned short*)take((size_t)INF * HID * 2);
    unsigned int* f0b = (unsigned int*)take((size_t)NN * HID * 2);  // bf16
    float* hbuf    = (float*)take((size_t)NN * HID * 4);            // gemm0 partial p0; edst alias; h
    float* part1   = (float*)take((size_t)NN * HID * 4);            // gemm0 partial p1; esrc alias
    unsigned int* hsA = (unsigned int*)take((size_t)NN * HID * 2);  // bf16
    unsigned int* hsB = (unsigned int*)take((size_t)NN * HID * 2);  // bf16

    // setup-phase aliases (dead before k_gemm0 writes them)
    uint2* edst = (uint2*)hbuf;   // NE * 8B = 6.4 MB <= 12.8 MB
    int* esrc   = (int*)part1;    // NE * 4B = 3.2 MB
    int* offD = off2;
    int* offS = off2 + SLEN;

    const int NB_W = (NN + 63) / 64;     // 782
    const int NB_L = (NN + TN - 1) / TN; // 1563
    const int NB_O = (NN + 127) / 128;   // 391
    const int NB_S2 = 2 * SLEN / 256;    // 392

    // bucketed CSR build (zero global atomics), single concatenated scan chain
    k_cnt<<<NBLK, 256, 0, stream>>>(src, dst, cnt2);
    gscanA<<<NB_S2, 256, 0, stream>>>(cnt2, sincl, bsum, 2 * SLEN);
    gscanB<<<1, 512, 0, stream>>>(bsum, NB_S2);
    gscanC<<<NB_S2, 256, 0, stream>>>(sincl, cnt2, bsum, off2, 2 * SLEN);
    k_scat<<<NBLK, 256, 0, stream>>>(src, dst, offD, offS, edst, esrc);
    k_build<<<2 * NBUK, 256, 0, stream>>>(edst, esrc, offD, offS, ndst, row_start, col, nsrc);

    k_wpp<<<(NL * 4 * 4 * 64 * 8 + INF * HID + 255) / 256, 256, 0, stream>>>(W1, W2, Win, wcat, wfrag);
    k_gemm0<<<2 * NB_W, 256, 0, stream>>>(feat, wfrag, hbuf, part1);
    k_gfin<<<(NN * 16 + 255) / 256, 256, 0, stream>>>(hbuf, part1, bin, nsrc, hsA, f0b);

    // ping-pong bf16 hs buffers (gathers read arbitrary rows; in-place would race)
    for (int l = 0; l < NL; ++l) {
        const unsigned int* hin = (l & 1) ? hsB : hsA;
        unsigned int* hout = (l & 1) ? hsA : hsB;
        float beta = logf(0.5f / (float)(l + 1) + 1.0f);
        float omb = 1.0f - beta;
        k_layer<<<NB_L, 256, 0, stream>>>(hin, col, row_start, ndst, f0b,
                                          wcat + (size_t)l * 4 * 4 * 64 * 8, bvec + l * HID,
                                          nsrc, omb, hbuf, hout, (l == NL - 1) ? 1 : 0);
    }
    k_out<<<NB_O, 256, 0, stream>>>(hbuf, Wout, bout, out);
}

// Round 13
// 546.979 us; speedup vs baseline: 2.2835x; 1.0183x over previous
//
#include <hip/hip_runtime.h>
#include <math.h>

#define NN 50000
#define NE 800000
#define INF 512
#define HID 64
#define OUTF 40
#define NL 16

// bucketed CSR build parameters
#define NBLK 256      // edge-blocks; NE = NBLK * EPB exactly
#define EPB 3125
#define NBUK 196      // node buckets of 256 (node >> 8); 196*256 = 50176 >= NN
#define SLEN (NBUK * NBLK)  // 50176 count/offset entries per direction

// layer tile
#define TN 32         // nodes per k_layer block
#define FP 72         // LDS row pitch in bf16 (144 B, 16B-aligned)

using short8 = __attribute__((ext_vector_type(8))) short;
using f32x4v = __attribute__((ext_vector_type(4))) float;

// bf16 helpers: RNE pack, cheap unpack
__device__ __forceinline__ unsigned int f2bf(float f) {
    unsigned int u = __float_as_uint(f);
    return (u + 0x7fffu + ((u >> 16) & 1u)) >> 16;
}
__device__ __forceinline__ float bflo(unsigned int w) { return __uint_as_float(w << 16); }
__device__ __forceinline__ float bfhi(unsigned int w) { return __uint_as_float(w & 0xffff0000u); }
__device__ __forceinline__ float bfs(unsigned short u) { return __uint_as_float(((unsigned)u) << 16); }

// ---------------- bucketed CSR build (no global atomics) ----------------

// per-(bucket, edge-block) counts; dst counts in cnt2[0..SLEN), src counts in cnt2[SLEN..2*SLEN)
__global__ __launch_bounds__(256) void k_cnt(const int* __restrict__ src, const int* __restrict__ dst,
                                             int* __restrict__ cnt2) {
    __shared__ int hD[NBUK];
    __shared__ int hS[NBUK];
    int t = threadIdx.x;
    int blk = blockIdx.x;
    if (t < NBUK) { hD[t] = 0; hS[t] = 0; }
    __syncthreads();
    int s0 = blk * EPB;
    for (int i = t; i < EPB; i += 256) {
        int e = s0 + i;
        atomicAdd(&hD[dst[e] >> 8], 1);
        atomicAdd(&hS[src[e] >> 8], 1);
    }
    __syncthreads();
    if (t < NBUK) {
        cnt2[t * NBLK + blk] = hD[t];
        cnt2[SLEN + t * NBLK + blk] = hS[t];
    }
}

// scan trio over the CONCATENATED 2*SLEN array (one chain instead of two)
__global__ __launch_bounds__(256) void gscanA(const int* __restrict__ in, int* __restrict__ incl,
                                              int* __restrict__ bsum, int len) {
    __shared__ int lds[256];
    int i = blockIdx.x * 256 + threadIdx.x;
    int v = (i < len) ? in[i] : 0;
    lds[threadIdx.x] = v;
    __syncthreads();
    for (int off = 1; off < 256; off <<= 1) {
        int t = (threadIdx.x >= off) ? lds[threadIdx.x - off] : 0;
        __syncthreads();
        lds[threadIdx.x] += t;
        __syncthreads();
    }
    if (i < len) incl[i] = lds[threadIdx.x];
    if (threadIdx.x == 255) bsum[blockIdx.x] = lds[255];
}

__global__ __launch_bounds__(512) void gscanB(int* __restrict__ bsum, int nb) {
    __shared__ int lds[512];
    int v = (threadIdx.x < nb) ? bsum[threadIdx.x] : 0;
    lds[threadIdx.x] = v;
    __syncthreads();
    for (int off = 1; off < 512; off <<= 1) {
        int t = (threadIdx.x >= off) ? lds[threadIdx.x - off] : 0;
        __syncthreads();
        lds[threadIdx.x] += t;
        __syncthreads();
    }
    if (threadIdx.x < nb) bsum[threadIdx.x] = lds[threadIdx.x] - v;  // exclusive
}

// exclusive offsets; second half (src direction) rebased by -NE (sum of all dst counts)
__global__ __launch_bounds__(256) void gscanC(const int* __restrict__ incl, const int* __restrict__ in,
                                              const int* __restrict__ bsum, int* __restrict__ off, int len) {
    int i = blockIdx.x * 256 + threadIdx.x;
    if (i < len) off[i] = incl[i] - in[i] + bsum[i >> 8] - ((i >= SLEN) ? NE : 0);
}

__global__ __launch_bounds__(256) void k_scat(const int* __restrict__ src, const int* __restrict__ dst,
                                              const int* __restrict__ offD, const int* __restrict__ offS,
                                              uint2* __restrict__ edst, int* __restrict__ esrc) {
    __shared__ int cD[NBUK];
    __shared__ int cS[NBUK];
    int t = threadIdx.x;
    int blk = blockIdx.x;
    if (t < NBUK) { cD[t] = 0; cS[t] = 0; }
    __syncthreads();
    int s0 = blk * EPB;
    for (int i = t; i < EPB; i += 256) {
        int e = s0 + i;
        int d = dst[e];
        int s = src[e];
        int bD = d >> 8;
        int r = atomicAdd(&cD[bD], 1);
        uint2 v;
        v.x = (unsigned)d;
        v.y = (unsigned)s;
        edst[offD[bD * NBLK + blk] + r] = v;
        int bS = s >> 8;
        int r2 = atomicAdd(&cS[bS], 1);
        esrc[offS[bS * NBLK + blk] + r2] = s;
    }
}

// merged: blocks [0,NBUK) build dst-side CSR (nd, row_start, col); blocks [NBUK,2*NBUK) build ns
__global__ __launch_bounds__(256) void k_build(const uint2* __restrict__ edst, const int* __restrict__ esrc,
                                               const int* __restrict__ offD, const int* __restrict__ offS,
                                               float* __restrict__ nd, int* __restrict__ row_start,
                                               int* __restrict__ col, float* __restrict__ ns) {
    __shared__ int cnt[256];
    __shared__ int ex[256];
    __shared__ int cur[256];
    int t = threadIdx.x;
    if (blockIdx.x < NBUK) {
        int b = blockIdx.x;
        int base = offD[b * NBLK];
        int end = (b < NBUK - 1) ? offD[(b + 1) * NBLK] : NE;
        cnt[t] = 0;
        __syncthreads();
        for (int p = base + t; p < end; p += 256) {
            uint2 ed = edst[p];
            atomicAdd(&cnt[ed.x & 255], 1);
        }
        __syncthreads();
        int v = cnt[t];
        ex[t] = v;
        __syncthreads();
        for (int off = 1; off < 256; off <<= 1) {
            int tv = (t >= off) ? ex[t - off] : 0;
            __syncthreads();
            ex[t] += tv;
            __syncthreads();
        }
        int excl = ex[t] - v;
        cur[t] = excl;
        int node = b * 256 + t;
        if (node < NN) {
            nd[node] = 1.0f / sqrtf((float)max(v, 1));
            row_start[node] = base + excl;
        }
        __syncthreads();
        for (int p = base + t; p < end; p += 256) {
            uint2 ed = edst[p];
            int r = atomicAdd(&cur[ed.x & 255], 1);
            col[base + r] = (int)ed.y;
        }
    } else {
        int b = blockIdx.x - NBUK;
        int base = offS[b * NBLK];
        int end = (b < NBUK - 1) ? offS[(b + 1) * NBLK] : NE;
        cnt[t] = 0;
        __syncthreads();
        for (int p = base + t; p < end; p += 256) {
            atomicAdd(&cnt[esrc[p] & 255], 1);
        }
        __syncthreads();
        int node = b * 256 + t;
        if (node < NN) ns[node] = 1.0f / sqrtf((float)max(cnt[t], 1));
    }
}

// ---------------- weight prep (merged): layer weights + Win fragments ----------------
// wc layout [l][s(4)][c(4)][lane(64)][j(8)], beta-scaled bf16, combined K=128 ([W1;W2]).
// wf layout [s(16)][c(4)][lane(64)][j(8)] for the h0 GEMM.
__global__ __launch_bounds__(256) void k_wpp(const float* __restrict__ W1, const float* __restrict__ W2,
                                             const float* __restrict__ Win,
                                             unsigned short* __restrict__ wc, unsigned short* __restrict__ wf) {
    int o = blockIdx.x * 256 + threadIdx.x;
    const int NWC = NL * 4 * 4 * 64 * 8;  // 131072
    if (o < NWC) {
        int j = o & 7;
        int ln = (o >> 3) & 63;
        int c = (o >> 9) & 3;
        int s = (o >> 11) & 3;
        int l = o >> 13;
        int colg = c * 16 + (ln & 15);
        int k = (s & 1) * 32 + ((ln >> 4) << 3) + j;
        float beta = logf(0.5f / (float)(l + 1) + 1.0f);
        const float* W = (s < 2) ? W1 : W2;
        wc[o] = (unsigned short)f2bf(beta * W[((size_t)l * 64 + k) * 64 + colg]);
    } else if (o < NWC + 16 * 4 * 64 * 8) {
        int o2 = o - NWC;
        int jj = o2 & 7;
        int l = (o2 >> 3) & 63;
        int c = (o2 >> 9) & 3;
        int s = o2 >> 11;
        int colg = c * 16 + (l & 15);
        int k = s * 32 + ((l >> 4) << 3) + jj;
        wf[o2] = (unsigned short)f2bf(Win[k * HID + colg]);
    }
}

// ---------------- h0 GEMM: bf16 MFMA (16x16x32), fragment-ordered LDS, K-split x2 ----------------
__global__ __launch_bounds__(256) void k_gemm0(const float* __restrict__ feat, const unsigned short* __restrict__ wf,
                                               float* __restrict__ p0, float* __restrict__ p1) {
    __shared__ unsigned int fS[2048];  // 8 KB: [s(2)][w(4)][lane(64)][4 uints = 8 bf16]
    int tid = threadIdx.x;
    int lane = tid & 63;
    int wv = tid >> 6;
    int bx = blockIdx.x;
    int w = bx >> 1;
    int kh = bx & 1;
    int nb = w * 64;
    f32x4v acc[4];
#pragma unroll
    for (int c = 0; c < 4; c++) acc[c] = {0.0f, 0.0f, 0.0f, 0.0f};

    int k0 = kh * 256;
    for (int kc = k0; kc < k0 + 256; kc += 64) {
        if (kc != k0) __syncthreads();
        float4 t[4];
#pragma unroll
        for (int j = 0; j < 4; j++) {
            int i = tid + j * 256;
            int nl = i >> 4;
            int k4 = i & 15;
            int n = min(nb + nl, NN - 1);
            t[j] = *(const float4*)(feat + (size_t)n * INF + kc + k4 * 4);
        }
#pragma unroll
        for (int j = 0; j < 4; j++) {
            int i = tid + j * 256;
            int nl = i >> 4;
            int kl = (i & 15) * 4;
            int s = kl >> 5;
            int kk = kl & 31;
            int lslot = (nl & 15) | ((kk >> 3) << 4);
            int dstu = (((s * 4 + (nl >> 4)) * 64 + lslot) << 2) + ((kk & 4) >> 1);
            fS[dstu] = f2bf(t[j].x) | (f2bf(t[j].y) << 16);
            fS[dstu + 1] = f2bf(t[j].z) | (f2bf(t[j].w) << 16);
        }
        __syncthreads();
#pragma unroll
        for (int s = 0; s < 2; ++s) {
            int sg = (kc + s * 32) >> 5;
            short8 af = *(const short8*)&fS[((s * 4 + wv) * 64 + lane) << 2];
            short8 bf[4];
#pragma unroll
            for (int c = 0; c < 4; ++c)
                bf[c] = *(const short8*)(wf + ((size_t)(sg * 4 + c) * 64 + lane) * 8);
#pragma unroll
            for (int c = 0; c < 4; ++c)
                acc[c] = __builtin_amdgcn_mfma_f32_16x16x32_bf16(af, bf[c], acc[c], 0, 0, 0);
        }
    }
    float* p = kh ? p1 : p0;
    int nodeb = nb + (wv << 4) + ((lane >> 4) << 2);
    int colb = lane & 15;
#pragma unroll
    for (int r = 0; r < 4; ++r) {
        int node = nodeb + r;
        if (node < NN) {
            float* pp = p + (size_t)node * HID + colb;
#pragma unroll
            for (int c = 0; c < 4; ++c) pp[c * 16] = acc[c][r];
        }
    }
}

// combine: p0+p1, +bias, relu, ns-scale, bf16 pack -> hs, f0b
__global__ __launch_bounds__(256) void k_gfin(const float* __restrict__ p0, const float* __restrict__ p1,
                                              const float* __restrict__ bin, const float* __restrict__ ns,
                                              unsigned int* __restrict__ hs, unsigned int* __restrict__ f0b) {
    int i = blockIdx.x * 256 + threadIdx.x;
    if (i >= NN * 16) return;
    int node = i >> 4;
    int q = i & 15;
    float4 a = ((const float4*)p0)[i];
    float4 b = ((const float4*)p1)[i];
    float4 bi = ((const float4*)bin)[q];
    float nsv = ns[node];
    float q0 = fmaxf(a.x + b.x + bi.x, 0.0f);
    float q1 = fmaxf(a.y + b.y + bi.y, 0.0f);
    float q2 = fmaxf(a.z + b.z + bi.z, 0.0f);
    float q3 = fmaxf(a.w + b.w + bi.w, 0.0f);
    uint2 pk;
    pk.x = f2bf(q0 * nsv) | (f2bf(q1 * nsv) << 16);
    pk.y = f2bf(q2 * nsv) | (f2bf(q3 * nsv) << 16);
    *(uint2*)(hs + (size_t)node * 32 + q * 2) = pk;
    uint2 pf;
    pf.x = f2bf(q0 * 0.1f) | (f2bf(q1 * 0.1f) << 16);
    pf.y = f2bf(q2 * 0.1f) | (f2bf(q3 * 0.1f) << 16);
    *(uint2*)(f0b + (size_t)node * 32 + q * 2) = pf;
}

// ---------------- fused layer: pair-gather agg (pv[8]: all 8 lane-gathers in flight) + MFMA matmul ----------------
// 256 threads = 4 waves, 32-node tile. 16-lane group per node; lanes ql<8 own the EVEN edges' rows,
// ql>=8 the ODD edges'. pv[8] issues ALL 8 of a lane's chunk-gathers back-to-back (one latency
// exposure per 16-edge chunk, vs two with pv[4]); accumulation order per lane is unchanged
// (ec = half, 2+half, ..., 14+half) -> bitwise-identical sums. __shfl_xor(8) merges even/odd.
// Then K=128 MFMA + fp32 identity epilogue.
__global__ __launch_bounds__(256) void k_layer(const unsigned int* __restrict__ hs_in, const int* __restrict__ col,
                                               const int* __restrict__ row_start,
                                               const float* __restrict__ nd, const unsigned int* __restrict__ f0b,
                                               const unsigned short* __restrict__ wc, const float* __restrict__ bias,
                                               const float* __restrict__ ns, float omb,
                                               float* __restrict__ h, unsigned int* __restrict__ hs_out, int write_h) {
    __shared__ unsigned short fS[TN * FP];   // agg f (scaled 0.9*nd), bf16
    __shared__ unsigned short f0S[TN * FP];  // f0, bf16
    __shared__ unsigned short oS[TN * FP];   // output bounce
    __shared__ float nsS[TN];
    int tid = threadIdx.x;
    int lane = tid & 63;
    int wv = tid >> 6;   // 0..3
    int nb = blockIdx.x * TN;
    int g = lane >> 4;   // group-in-wave 0..3
    int ql = lane & 15;
    int half = ql >> 3;  // 0: even edges, 1: odd edges
    int qb = ql & 7;     // 16B segment: dims [8qb, 8qb+8)

    // stage f0 tile: thread i -> node i>>3, 16B segment i&7
    {
        int nl = tid >> 3, sg = tid & 7;
        int n = min(nb + nl, NN - 1);
        uint4 v = *(const uint4*)(f0b + (size_t)n * 32 + sg * 4);
        *(uint4*)&f0S[nl * FP + sg * 8] = v;
    }
    if (tid < TN) nsS[tid] = ns[min(nb + tid, NN - 1)];

    // hoist both passes' metadata + first-chunk col indices
    int nlP[2], baseP[2], degP[2], idxP[2];
    float ndP[2];
#pragma unroll
    for (int p = 0; p < 2; ++p) {
        int nl = p * 16 + wv * 4 + g;
        int n = min(nb + nl, NN - 1);
        nlP[p] = nl;
        int base = row_start[n];
        int nxt = (n < NN - 1) ? row_start[n + 1] : NE;
        baseP[p] = base;
        degP[p] = nxt - base;
        ndP[p] = nd[n];
    }
#pragma unroll
    for (int p = 0; p < 2; ++p) {
        idxP[p] = (ql < min(16, degP[p])) ? col[baseP[p] + ql] : 0;
    }

    // pair-gather aggregation: 8 gathers in flight per lane per chunk
#pragma unroll
    for (int pass = 0; pass < 2; ++pass) {
        int base = baseP[pass];
        int deg = degP[pass];
        int idxv = idxP[pass];
        float a0 = 0.f, a1 = 0.f, a2 = 0.f, a3 = 0.f, a4 = 0.f, a5 = 0.f, a6 = 0.f, a7 = 0.f;
        for (int done = 0; done < deg; done += 16) {
            int cnt = min(16, deg - done);
            int nxt = done + 16;
            int idxn = 0;
            if (nxt < deg && ql < deg - nxt) idxn = col[base + nxt + ql];
            uint4 pv[8];
#pragma unroll
            for (int e = 0; e < 8; ++e) {
                int ec = 2 * e + half;
                int s = __shfl(idxv, (g << 4) | ec, 64);
                uint4 v = {0u, 0u, 0u, 0u};
                if (ec < cnt) v = *(const uint4*)(hs_in + (size_t)s * 32 + qb * 4);
                pv[e] = v;
            }
#pragma unroll
            for (int e = 0; e < 8; ++e) {
                a0 += bflo(pv[e].x); a1 += bfhi(pv[e].x);
                a2 += bflo(pv[e].y); a3 += bfhi(pv[e].y);
                a4 += bflo(pv[e].z); a5 += bfhi(pv[e].z);
                a6 += bflo(pv[e].w); a7 += bfhi(pv[e].w);
            }
            idxv = idxn;
        }
        // merge even/odd partials across ql^8 (same dims on both lanes)
        a0 += __shfl_xor(a0, 8, 64);
        a1 += __shfl_xor(a1, 8, 64);
        a2 += __shfl_xor(a2, 8, 64);
        a3 += __shfl_xor(a3, 8, 64);
        a4 += __shfl_xor(a4, 8, 64);
        a5 += __shfl_xor(a5, 8, 64);
        a6 += __shfl_xor(a6, 8, 64);
        a7 += __shfl_xor(a7, 8, 64);
        float sc = 0.9f * ndP[pass];
        int nl = nlP[pass];
        if (half == 0) {
            uint4 w;
            w.x = f2bf(a0 * sc) | (f2bf(a1 * sc) << 16);
            w.y = f2bf(a2 * sc) | (f2bf(a3 * sc) << 16);
            w.z = f2bf(a4 * sc) | (f2bf(a5 * sc) << 16);
            w.w = f2bf(a6 * sc) | (f2bf(a7 * sc) << 16);
            *(uint4*)&fS[nl * FP + qb * 8] = w;
        }
    }
    __syncthreads();

    // MFMA: wave wv owns col-tile wv; m-tiles = node halves; K=128 = 4 steps ([f;f0] x [W1;W2])
    int hi = lane >> 4;
    int lo = lane & 15;
    f32x4v acc0 = {0.0f, 0.0f, 0.0f, 0.0f};
    f32x4v acc1 = {0.0f, 0.0f, 0.0f, 0.0f};
#pragma unroll
    for (int s = 0; s < 4; ++s) {
        short8 bf = *(const short8*)(wc + ((size_t)(s * 4 + wv) * 64 + lane) * 8);
        const unsigned short* ab = (s < 2) ? fS : f0S;
        int ko = (s & 1) * 32;
        short8 a0 = *(const short8*)&ab[(0 * 16 + lo) * FP + ko + hi * 8];
        short8 a1 = *(const short8*)&ab[(1 * 16 + lo) * FP + ko + hi * 8];
        acc0 = __builtin_amdgcn_mfma_f32_16x16x32_bf16(a0, bf, acc0, 0, 0, 0);
        acc1 = __builtin_amdgcn_mfma_f32_16x16x32_bf16(a1, bf, acc1, 0, 0, 0);
    }

    // epilogue: + (1-beta)(f+f0) + bias, relu; oS = bf16(q*ns); optional h write (fp32)
    int colg = wv * 16 + lo;
    float bv = bias[colg];
#pragma unroll
    for (int m = 0; m < 2; ++m) {
        f32x4v a = m ? acc1 : acc0;
#pragma unroll
        for (int r = 0; r < 4; ++r) {
            int rowl = m * 16 + hi * 4 + r;
            float fv = bfs(fS[rowl * FP + colg]);
            float f0v = bfs(f0S[rowl * FP + colg]);
            float q = fmaxf(a[r] + omb * (fv + f0v) + bv, 0.0f);
            oS[rowl * FP + colg] = (unsigned short)f2bf(q * nsS[rowl]);
            if (write_h) {
                int node = nb + rowl;
                if (node < NN) h[(size_t)node * HID + colg] = q;
            }
        }
    }
    __syncthreads();

    // coalesced hs_out write: thread i -> node i>>3, 16B segment i&7
    {
        int nl = tid >> 3, sg = tid & 7;
        int node = nb + nl;
        if (node < NN) {
            uint4 v = *(const uint4*)&oS[nl * FP + sg * 8];
            *(uint4*)(hs_out + (size_t)node * 32 + sg * 4) = v;
        }
    }
}

// ---------------- output: block = 128 nodes; wave pair splits the 40 cols; LDS lse reduce ----------------
__global__ __launch_bounds__(256) void k_out(const float* __restrict__ h, const float* __restrict__ Wout,
                                             const float* __restrict__ bout, float* __restrict__ out) {
    __shared__ float red_mx[4][64];
    __shared__ float red_s[4][64];
    int tid = threadIdx.x;
    int lane = tid & 63;
    int wv = tid >> 6;
    int half = wv & 1;
    int grp = wv >> 1;
    int node = blockIdx.x * 128 + grp * 64 + lane;
    int nodec = min(node, NN - 1);
    float acc[20];
#pragma unroll
    for (int c = 0; c < 20; c++) acc[c] = 0.0f;
    const float4* hr = (const float4*)(h + (size_t)nodec * HID);
    const float* wb = Wout + half * 20;
    for (int kk = 0; kk < HID / 4; ++kk) {
        float4 a = hr[kk];
        float av[4] = {a.x, a.y, a.z, a.w};
#pragma unroll
        for (int j = 0; j < 4; j++) {
            const float* wr = wb + (size_t)(kk * 4 + j) * OUTF;
#pragma unroll
            for (int c = 0; c < 20; c++) acc[c] += av[j] * wr[c];
        }
    }
    const float* bp = bout + half * 20;
#pragma unroll
    for (int c = 0; c < 20; c++) acc[c] += bp[c];
    float mx = acc[0];
#pragma unroll
    for (int c = 1; c < 20; c++) mx = fmaxf(mx, acc[c]);
    red_mx[wv][lane] = mx;
    __syncthreads();
    float gmx = fmaxf(mx, red_mx[wv ^ 1][lane]);
    float s = 0.0f;
#pragma unroll
    for (int c = 0; c < 20; c++) s += expf(acc[c] - gmx);
    red_s[wv][lane] = s;
    __syncthreads();
    float lse = logf(s + red_s[wv ^ 1][lane]) + gmx;
    if (node < NN) {
        float4* op = (float4*)(out + (size_t)node * OUTF + half * 20);
#pragma unroll
        for (int q = 0; q < 5; q++) {
            float4 v;
            v.x = acc[q * 4 + 0] - lse;
            v.y = acc[q * 4 + 1] - lse;
            v.z = acc[q * 4 + 2] - lse;
            v.w = acc[q * 4 + 3] - lse;
            op[q] = v;
        }
    }
}

extern "C" void kernel_launch(void* const* d_in, const int* in_sizes, int n_in,
                              void* d_out, int out_size, void* d_ws, size_t ws_size,
                              hipStream_t stream) {
    const float* feat = (const float*)d_in[0];
    const float* Win  = (const float*)d_in[1];
    const float* bin  = (const float*)d_in[2];
    const float* W1   = (const float*)d_in[3];
    const float* W2   = (const float*)d_in[4];
    const float* bvec = (const float*)d_in[5];
    const float* Wout = (const float*)d_in[6];
    const float* bout = (const float*)d_in[7];
    const int*   src  = (const int*)d_in[8];
    const int*   dst  = (const int*)d_in[9];
    float* out = (float*)d_out;

    char* ws = (char*)d_ws;
    size_t off = 0;
    auto take = [&](size_t bytes) {
        void* p = ws + off;
        off += (bytes + 255) & ~(size_t)255;
        return p;
    };
    int* bsum      = (int*)take(512 * 4);
    int* row_start = (int*)take(NN * 4);
    int* col       = (int*)take(NE * 4);
    float* nsrc    = (float*)take(NN * 4);
    float* ndst    = (float*)take(NN * 4);
    int* cnt2      = (int*)take(2 * SLEN * 4);   // [cntD | cntS]
    int* off2      = (int*)take(2 * SLEN * 4);   // [offD | offS]
    int* sincl     = (int*)take(2 * SLEN * 4);
    unsigned short* wcat  = (unsigned short*)take((size_t)NL * 4 * 4 * 64 * 8 * 2);  // 256 KB bf16 frags
    unsigned short* wfrag = (unsigned short*)take((size_t)INF * HID * 2);
    unsigned int* f0b = (unsigned int*)take((size_t)NN * HID * 2);  // bf16
    float* hbuf    = (float*)take((size_t)NN * HID * 4);            // gemm0 partial p0; edst alias; h
    float* part1   = (float*)take((size_t)NN * HID * 4);            // gemm0 partial p1; esrc alias
    unsigned int* hsA = (unsigned int*)take((size_t)NN * HID * 2);  // bf16
    unsigned int* hsB = (unsigned int*)take((size_t)NN * HID * 2);  // bf16

    // setup-phase aliases (dead before k_gemm0 writes them)
    uint2* edst = (uint2*)hbuf;   // NE * 8B = 6.4 MB <= 12.8 MB
    int* esrc   = (int*)part1;    // NE * 4B = 3.2 MB
    int* offD = off2;
    int* offS = off2 + SLEN;

    const int NB_W = (NN + 63) / 64;     // 782
    const int NB_L = (NN + TN - 1) / TN; // 1563
    const int NB_O = (NN + 127) / 128;   // 391
    const int NB_S2 = 2 * SLEN / 256;    // 392

    // bucketed CSR build (zero global atomics), single concatenated scan chain
    k_cnt<<<NBLK, 256, 0, stream>>>(src, dst, cnt2);
    gscanA<<<NB_S2, 256, 0, stream>>>(cnt2, sincl, bsum, 2 * SLEN);
    gscanB<<<1, 512, 0, stream>>>(bsum, NB_S2);
    gscanC<<<NB_S2, 256, 0, stream>>>(sincl, cnt2, bsum, off2, 2 * SLEN);
    k_scat<<<NBLK, 256, 0, stream>>>(src, dst, offD, offS, edst, esrc);
    k_build<<<2 * NBUK, 256, 0, stream>>>(edst, esrc, offD, offS, ndst, row_start, col, nsrc);

    k_wpp<<<(NL * 4 * 4 * 64 * 8 + INF * HID + 255) / 256, 256, 0, stream>>>(W1, W2, Win, wcat, wfrag);
    k_gemm0<<<2 * NB_W, 256, 0, stream>>>(feat, wfrag, hbuf, part1);
    k_gfin<<<(NN * 16 + 255) / 256, 256, 0, stream>>>(hbuf, part1, bin, nsrc, hsA, f0b);

    // ping-pong bf16 hs buffers (gathers read arbitrary rows; in-place would race)
    for (int l = 0; l < NL; ++l) {
        const unsigned int* hin = (l & 1) ? hsB : hsA;
        unsigned int* hout = (l & 1) ? hsA : hsB;
        float beta = logf(0.5f / (float)(l + 1) + 1.0f);
        float omb = 1.0f - beta;
        k_layer<<<NB_L, 256, 0, stream>>>(hin, col, row_start, ndst, f0b,
                                          wcat + (size_t)l * 4 * 4 * 64 * 8, bvec + l * HID,
                                          nsrc, omb, hbuf, hout, (l == NL - 1) ? 1 : 0);
    }
    k_out<<<NB_O, 256, 0, stream>>>(hbuf, Wout, bout, out);
}

// Round 14
// 541.483 us; speedup vs baseline: 2.3067x; 1.0101x over previous
//
#include <hip/hip_runtime.h>
#include <math.h>

#define NN 50000
#define NE 800000
#define INF 512
#define HID 64
#define OUTF 40
#define NL 16

// bucketed CSR build parameters
#define NBLK 256      // edge-blocks; NE = NBLK * EPB exactly
#define EPB 3125
#define NBUK 196      // node buckets of 256 (node >> 8); 196*256 = 50176 >= NN
#define SLEN (NBUK * NBLK)  // 50176 count/offset entries per direction

// layer tile: TN=16 -> 3125 blocks = 12.2/CU, saturates the 8-block/CU residency cap
// (32 waves/CU vs 24.4 grid-limited at TN=32). Gather is latency-bound -> more TLP.
#define TN 16         // nodes per k_layer block
#define FP 72         // LDS row pitch in bf16 (144 B, 16B-aligned)

using short8 = __attribute__((ext_vector_type(8))) short;
using f32x4v = __attribute__((ext_vector_type(4))) float;

// bf16 helpers: RNE pack, cheap unpack
__device__ __forceinline__ unsigned int f2bf(float f) {
    unsigned int u = __float_as_uint(f);
    return (u + 0x7fffu + ((u >> 16) & 1u)) >> 16;
}
__device__ __forceinline__ float bflo(unsigned int w) { return __uint_as_float(w << 16); }
__device__ __forceinline__ float bfhi(unsigned int w) { return __uint_as_float(w & 0xffff0000u); }
__device__ __forceinline__ float bfs(unsigned short u) { return __uint_as_float(((unsigned)u) << 16); }

// ---------------- bucketed CSR build (no global atomics) ----------------

// per-(bucket, edge-block) counts; dst counts in cnt2[0..SLEN), src counts in cnt2[SLEN..2*SLEN)
__global__ __launch_bounds__(256) void k_cnt(const int* __restrict__ src, const int* __restrict__ dst,
                                             int* __restrict__ cnt2) {
    __shared__ int hD[NBUK];
    __shared__ int hS[NBUK];
    int t = threadIdx.x;
    int blk = blockIdx.x;
    if (t < NBUK) { hD[t] = 0; hS[t] = 0; }
    __syncthreads();
    int s0 = blk * EPB;
    for (int i = t; i < EPB; i += 256) {
        int e = s0 + i;
        atomicAdd(&hD[dst[e] >> 8], 1);
        atomicAdd(&hS[src[e] >> 8], 1);
    }
    __syncthreads();
    if (t < NBUK) {
        cnt2[t * NBLK + blk] = hD[t];
        cnt2[SLEN + t * NBLK + blk] = hS[t];
    }
}

// scan trio over the CONCATENATED 2*SLEN array (one chain instead of two)
__global__ __launch_bounds__(256) void gscanA(const int* __restrict__ in, int* __restrict__ incl,
                                              int* __restrict__ bsum, int len) {
    __shared__ int lds[256];
    int i = blockIdx.x * 256 + threadIdx.x;
    int v = (i < len) ? in[i] : 0;
    lds[threadIdx.x] = v;
    __syncthreads();
    for (int off = 1; off < 256; off <<= 1) {
        int t = (threadIdx.x >= off) ? lds[threadIdx.x - off] : 0;
        __syncthreads();
        lds[threadIdx.x] += t;
        __syncthreads();
    }
    if (i < len) incl[i] = lds[threadIdx.x];
    if (threadIdx.x == 255) bsum[blockIdx.x] = lds[255];
}

__global__ __launch_bounds__(512) void gscanB(int* __restrict__ bsum, int nb) {
    __shared__ int lds[512];
    int v = (threadIdx.x < nb) ? bsum[threadIdx.x] : 0;
    lds[threadIdx.x] = v;
    __syncthreads();
    for (int off = 1; off < 512; off <<= 1) {
        int t = (threadIdx.x >= off) ? lds[threadIdx.x - off] : 0;
        __syncthreads();
        lds[threadIdx.x] += t;
        __syncthreads();
    }
    if (threadIdx.x < nb) bsum[threadIdx.x] = lds[threadIdx.x] - v;  // exclusive
}

// exclusive offsets; second half (src direction) rebased by -NE (sum of all dst counts)
__global__ __launch_bounds__(256) void gscanC(const int* __restrict__ incl, const int* __restrict__ in,
                                              const int* __restrict__ bsum, int* __restrict__ off, int len) {
    int i = blockIdx.x * 256 + threadIdx.x;
    if (i < len) off[i] = incl[i] - in[i] + bsum[i >> 8] - ((i >= SLEN) ? NE : 0);
}

__global__ __launch_bounds__(256) void k_scat(const int* __restrict__ src, const int* __restrict__ dst,
                                              const int* __restrict__ offD, const int* __restrict__ offS,
                                              uint2* __restrict__ edst, int* __restrict__ esrc) {
    __shared__ int cD[NBUK];
    __shared__ int cS[NBUK];
    int t = threadIdx.x;
    int blk = blockIdx.x;
    if (t < NBUK) { cD[t] = 0; cS[t] = 0; }
    __syncthreads();
    int s0 = blk * EPB;
    for (int i = t; i < EPB; i += 256) {
        int e = s0 + i;
        int d = dst[e];
        int s = src[e];
        int bD = d >> 8;
        int r = atomicAdd(&cD[bD], 1);
        uint2 v;
        v.x = (unsigned)d;
        v.y = (unsigned)s;
        edst[offD[bD * NBLK + blk] + r] = v;
        int bS = s >> 8;
        int r2 = atomicAdd(&cS[bS], 1);
        esrc[offS[bS * NBLK + blk] + r2] = s;
    }
}

// merged: blocks [0,NBUK) build dst-side CSR (nd, row_start, col); blocks [NBUK,2*NBUK) build ns
__global__ __launch_bounds__(256) void k_build(const uint2* __restrict__ edst, const int* __restrict__ esrc,
                                               const int* __restrict__ offD, const int* __restrict__ offS,
                                               float* __restrict__ nd, int* __restrict__ row_start,
                                               int* __restrict__ col, float* __restrict__ ns) {
    __shared__ int cnt[256];
    __shared__ int ex[256];
    __shared__ int cur[256];
    int t = threadIdx.x;
    if (blockIdx.x < NBUK) {
        int b = blockIdx.x;
        int base = offD[b * NBLK];
        int end = (b < NBUK - 1) ? offD[(b + 1) * NBLK] : NE;
        cnt[t] = 0;
        __syncthreads();
        for (int p = base + t; p < end; p += 256) {
            uint2 ed = edst[p];
            atomicAdd(&cnt[ed.x & 255], 1);
        }
        __syncthreads();
        int v = cnt[t];
        ex[t] = v;
        __syncthreads();
        for (int off = 1; off < 256; off <<= 1) {
            int tv = (t >= off) ? ex[t - off] : 0;
            __syncthreads();
            ex[t] += tv;
            __syncthreads();
        }
        int excl = ex[t] - v;
        cur[t] = excl;
        int node = b * 256 + t;
        if (node < NN) {
            nd[node] = 1.0f / sqrtf((float)max(v, 1));
            row_start[node] = base + excl;
        }
        __syncthreads();
        for (int p = base + t; p < end; p += 256) {
            uint2 ed = edst[p];
            int r = atomicAdd(&cur[ed.x & 255], 1);
            col[base + r] = (int)ed.y;
        }
    } else {
        int b = blockIdx.x - NBUK;
        int base = offS[b * NBLK];
        int end = (b < NBUK - 1) ? offS[(b + 1) * NBLK] : NE;
        cnt[t] = 0;
        __syncthreads();
        for (int p = base + t; p < end; p += 256) {
            atomicAdd(&cnt[esrc[p] & 255], 1);
        }
        __syncthreads();
        int node = b * 256 + t;
        if (node < NN) ns[node] = 1.0f / sqrtf((float)max(cnt[t], 1));
    }
}

// ---------------- weight prep (merged): layer weights + Win fragments ----------------
// wc layout [l][s(4)][c(4)][lane(64)][j(8)], beta-scaled bf16, combined K=128 ([W1;W2]).
// wf layout [s(16)][c(4)][lane(64)][j(8)] for the h0 GEMM.
__global__ __launch_bounds__(256) void k_wpp(const float* __restrict__ W1, const float* __restrict__ W2,
                                             const float* __restrict__ Win,
                                             unsigned short* __restrict__ wc, unsigned short* __restrict__ wf) {
    int o = blockIdx.x * 256 + threadIdx.x;
    const int NWC = NL * 4 * 4 * 64 * 8;  // 131072
    if (o < NWC) {
        int j = o & 7;
        int ln = (o >> 3) & 63;
        int c = (o >> 9) & 3;
        int s = (o >> 11) & 3;
        int l = o >> 13;
        int colg = c * 16 + (ln & 15);
        int k = (s & 1) * 32 + ((ln >> 4) << 3) + j;
        float beta = logf(0.5f / (float)(l + 1) + 1.0f);
        const float* W = (s < 2) ? W1 : W2;
        wc[o] = (unsigned short)f2bf(beta * W[((size_t)l * 64 + k) * 64 + colg]);
    } else if (o < NWC + 16 * 4 * 64 * 8) {
        int o2 = o - NWC;
        int jj = o2 & 7;
        int l = (o2 >> 3) & 63;
        int c = (o2 >> 9) & 3;
        int s = o2 >> 11;
        int colg = c * 16 + (l & 15);
        int k = s * 32 + ((l >> 4) << 3) + jj;
        wf[o2] = (unsigned short)f2bf(Win[k * HID + colg]);
    }
}

// ---------------- h0 GEMM: bf16 MFMA (16x16x32), fragment-ordered LDS, K-split x2 ----------------
__global__ __launch_bounds__(256) void k_gemm0(const float* __restrict__ feat, const unsigned short* __restrict__ wf,
                                               float* __restrict__ p0, float* __restrict__ p1) {
    __shared__ unsigned int fS[2048];  // 8 KB: [s(2)][w(4)][lane(64)][4 uints = 8 bf16]
    int tid = threadIdx.x;
    int lane = tid & 63;
    int wv = tid >> 6;
    int bx = blockIdx.x;
    int w = bx >> 1;
    int kh = bx & 1;
    int nb = w * 64;
    f32x4v acc[4];
#pragma unroll
    for (int c = 0; c < 4; c++) acc[c] = {0.0f, 0.0f, 0.0f, 0.0f};

    int k0 = kh * 256;
    for (int kc = k0; kc < k0 + 256; kc += 64) {
        if (kc != k0) __syncthreads();
        float4 t[4];
#pragma unroll
        for (int j = 0; j < 4; j++) {
            int i = tid + j * 256;
            int nl = i >> 4;
            int k4 = i & 15;
            int n = min(nb + nl, NN - 1);
            t[j] = *(const float4*)(feat + (size_t)n * INF + kc + k4 * 4);
        }
#pragma unroll
        for (int j = 0; j < 4; j++) {
            int i = tid + j * 256;
            int nl = i >> 4;
            int kl = (i & 15) * 4;
            int s = kl >> 5;
            int kk = kl & 31;
            int lslot = (nl & 15) | ((kk >> 3) << 4);
            int dstu = (((s * 4 + (nl >> 4)) * 64 + lslot) << 2) + ((kk & 4) >> 1);
            fS[dstu] = f2bf(t[j].x) | (f2bf(t[j].y) << 16);
            fS[dstu + 1] = f2bf(t[j].z) | (f2bf(t[j].w) << 16);
        }
        __syncthreads();
#pragma unroll
        for (int s = 0; s < 2; ++s) {
            int sg = (kc + s * 32) >> 5;
            short8 af = *(const short8*)&fS[((s * 4 + wv) * 64 + lane) << 2];
            short8 bf[4];
#pragma unroll
            for (int c = 0; c < 4; ++c)
                bf[c] = *(const short8*)(wf + ((size_t)(sg * 4 + c) * 64 + lane) * 8);
#pragma unroll
            for (int c = 0; c < 4; ++c)
                acc[c] = __builtin_amdgcn_mfma_f32_16x16x32_bf16(af, bf[c], acc[c], 0, 0, 0);
        }
    }
    float* p = kh ? p1 : p0;
    int nodeb = nb + (wv << 4) + ((lane >> 4) << 2);
    int colb = lane & 15;
#pragma unroll
    for (int r = 0; r < 4; ++r) {
        int node = nodeb + r;
        if (node < NN) {
            float* pp = p + (size_t)node * HID + colb;
#pragma unroll
            for (int c = 0; c < 4; ++c) pp[c * 16] = acc[c][r];
        }
    }
}

// combine: p0+p1, +bias, relu, ns-scale, bf16 pack -> hs, f0b
__global__ __launch_bounds__(256) void k_gfin(const float* __restrict__ p0, const float* __restrict__ p1,
                                              const float* __restrict__ bin, const float* __restrict__ ns,
                                              unsigned int* __restrict__ hs, unsigned int* __restrict__ f0b) {
    int i = blockIdx.x * 256 + threadIdx.x;
    if (i >= NN * 16) return;
    int node = i >> 4;
    int q = i & 15;
    float4 a = ((const float4*)p0)[i];
    float4 b = ((const float4*)p1)[i];
    float4 bi = ((const float4*)bin)[q];
    float nsv = ns[node];
    float q0 = fmaxf(a.x + b.x + bi.x, 0.0f);
    float q1 = fmaxf(a.y + b.y + bi.y, 0.0f);
    float q2 = fmaxf(a.z + b.z + bi.z, 0.0f);
    float q3 = fmaxf(a.w + b.w + bi.w, 0.0f);
    uint2 pk;
    pk.x = f2bf(q0 * nsv) | (f2bf(q1 * nsv) << 16);
    pk.y = f2bf(q2 * nsv) | (f2bf(q3 * nsv) << 16);
    *(uint2*)(hs + (size_t)node * 32 + q * 2) = pk;
    uint2 pf;
    pf.x = f2bf(q0 * 0.1f) | (f2bf(q1 * 0.1f) << 16);
    pf.y = f2bf(q2 * 0.1f) | (f2bf(q3 * 0.1f) << 16);
    *(uint2*)(f0b + (size_t)node * 32 + q * 2) = pf;
}

// ---------------- fused layer: TN=16 (full occupancy), pair-gather pv[8] + MFMA matmul ----------------
// 256 threads = 4 waves, 16-node tile -> 3125 blocks (= 50000/16 exactly), 12.2 blocks/CU streaming
// through the 8-resident cap = 32 waves/CU (was 24.4 grid-limited at TN=32). One 16-lane group per
// node, SINGLE pass. Inner gather machinery identical to R13 (pv[8], bitwise-identical sums).
__global__ __launch_bounds__(256) void k_layer(const unsigned int* __restrict__ hs_in, const int* __restrict__ col,
                                               const int* __restrict__ row_start,
                                               const float* __restrict__ nd, const unsigned int* __restrict__ f0b,
                                               const unsigned short* __restrict__ wc, const float* __restrict__ bias,
                                               const float* __restrict__ ns, float omb,
                                               float* __restrict__ h, unsigned int* __restrict__ hs_out, int write_h) {
    __shared__ unsigned short fS[TN * FP];   // agg f (scaled 0.9*nd), bf16
    __shared__ unsigned short f0S[TN * FP];  // f0, bf16
    __shared__ unsigned short oS[TN * FP];   // output bounce
    __shared__ float nsS[TN];
    int tid = threadIdx.x;
    int lane = tid & 63;
    int wv = tid >> 6;   // 0..3
    int nb = blockIdx.x * TN;
    int g = lane >> 4;   // group-in-wave 0..3
    int ql = lane & 15;
    int half = ql >> 3;  // 0: even edges, 1: odd edges
    int qb = ql & 7;     // 16B segment: dims [8qb, 8qb+8)

    // stage f0 tile: 16 nodes x 8 segments = 128 slots
    if (tid < TN * 8) {
        int nl = tid >> 3, sg = tid & 7;
        int n = nb + nl;  // always < NN (50000 = 3125*16 exactly)
        uint4 v = *(const uint4*)(f0b + (size_t)n * 32 + sg * 4);
        *(uint4*)&f0S[nl * FP + sg * 8] = v;
    }
    if (tid < TN) nsS[tid] = ns[nb + tid];

    // this group's node metadata + first-chunk col indices
    int nl = wv * 4 + g;           // 0..15
    int n = nb + nl;
    int base = row_start[n];
    int nxt0 = (n < NN - 1) ? row_start[n + 1] : NE;
    int deg = nxt0 - base;
    float ndv = nd[n];
    int idxv = (ql < min(16, deg)) ? col[base + ql] : 0;

    // pair-gather aggregation: 8 gathers in flight per lane per chunk
    {
        float a0 = 0.f, a1 = 0.f, a2 = 0.f, a3 = 0.f, a4 = 0.f, a5 = 0.f, a6 = 0.f, a7 = 0.f;
        for (int done = 0; done < deg; done += 16) {
            int cnt = min(16, deg - done);
            int nxt = done + 16;
            int idxn = 0;
            if (nxt < deg && ql < deg - nxt) idxn = col[base + nxt + ql];
            uint4 pv[8];
#pragma unroll
            for (int e = 0; e < 8; ++e) {
                int ec = 2 * e + half;
                int s = __shfl(idxv, (g << 4) | ec, 64);
                uint4 v = {0u, 0u, 0u, 0u};
                if (ec < cnt) v = *(const uint4*)(hs_in + (size_t)s * 32 + qb * 4);
                pv[e] = v;
            }
#pragma unroll
            for (int e = 0; e < 8; ++e) {
                a0 += bflo(pv[e].x); a1 += bfhi(pv[e].x);
                a2 += bflo(pv[e].y); a3 += bfhi(pv[e].y);
                a4 += bflo(pv[e].z); a5 += bfhi(pv[e].z);
                a6 += bflo(pv[e].w); a7 += bfhi(pv[e].w);
            }
            idxv = idxn;
        }
        // merge even/odd partials across ql^8 (same dims on both lanes)
        a0 += __shfl_xor(a0, 8, 64);
        a1 += __shfl_xor(a1, 8, 64);
        a2 += __shfl_xor(a2, 8, 64);
        a3 += __shfl_xor(a3, 8, 64);
        a4 += __shfl_xor(a4, 8, 64);
        a5 += __shfl_xor(a5, 8, 64);
        a6 += __shfl_xor(a6, 8, 64);
        a7 += __shfl_xor(a7, 8, 64);
        float sc = 0.9f * ndv;
        if (half == 0) {
            uint4 w;
            w.x = f2bf(a0 * sc) | (f2bf(a1 * sc) << 16);
            w.y = f2bf(a2 * sc) | (f2bf(a3 * sc) << 16);
            w.z = f2bf(a4 * sc) | (f2bf(a5 * sc) << 16);
            w.w = f2bf(a6 * sc) | (f2bf(a7 * sc) << 16);
            *(uint4*)&fS[nl * FP + qb * 8] = w;
        }
    }
    __syncthreads();

    // MFMA: wave wv owns col-tile wv (cols wv*16..+15); single 16-row m-tile; K=128 = 4 steps
    int hi = lane >> 4;
    int lo = lane & 15;
    f32x4v acc0 = {0.0f, 0.0f, 0.0f, 0.0f};
#pragma unroll
    for (int s = 0; s < 4; ++s) {
        short8 bf = *(const short8*)(wc + ((size_t)(s * 4 + wv) * 64 + lane) * 8);
        const unsigned short* ab = (s < 2) ? fS : f0S;
        int ko = (s & 1) * 32;
        short8 a0 = *(const short8*)&ab[lo * FP + ko + hi * 8];
        acc0 = __builtin_amdgcn_mfma_f32_16x16x32_bf16(a0, bf, acc0, 0, 0, 0);
    }

    // epilogue: + (1-beta)(f+f0) + bias, relu; oS = bf16(q*ns); optional h write (fp32)
    int colg = wv * 16 + lo;
    float bv = bias[colg];
#pragma unroll
    for (int r = 0; r < 4; ++r) {
        int rowl = hi * 4 + r;  // 0..15
        float fv = bfs(fS[rowl * FP + colg]);
        float f0v = bfs(f0S[rowl * FP + colg]);
        float q = fmaxf(acc0[r] + omb * (fv + f0v) + bv, 0.0f);
        oS[rowl * FP + colg] = (unsigned short)f2bf(q * nsS[rowl]);
        if (write_h) {
            h[(size_t)(nb + rowl) * HID + colg] = q;
        }
    }
    __syncthreads();

    // coalesced hs_out write: 16 nodes x 8 segments
    if (tid < TN * 8) {
        int nl2 = tid >> 3, sg = tid & 7;
        uint4 v = *(const uint4*)&oS[nl2 * FP + sg * 8];
        *(uint4*)(hs_out + (size_t)(nb + nl2) * 32 + sg * 4) = v;
    }
}

// ---------------- output: block = 128 nodes; wave pair splits the 40 cols; LDS lse reduce ----------------
__global__ __launch_bounds__(256) void k_out(const float* __restrict__ h, const float* __restrict__ Wout,
                                             const float* __restrict__ bout, float* __restrict__ out) {
    __shared__ float red_mx[4][64];
    __shared__ float red_s[4][64];
    int tid = threadIdx.x;
    int lane = tid & 63;
    int wv = tid >> 6;
    int half = wv & 1;
    int grp = wv >> 1;
    int node = blockIdx.x * 128 + grp * 64 + lane;
    int nodec = min(node, NN - 1);
    float acc[20];
#pragma unroll
    for (int c = 0; c < 20; c++) acc[c] = 0.0f;
    const float4* hr = (const float4*)(h + (size_t)nodec * HID);
    const float* wb = Wout + half * 20;
    for (int kk = 0; kk < HID / 4; ++kk) {
        float4 a = hr[kk];
        float av[4] = {a.x, a.y, a.z, a.w};
#pragma unroll
        for (int j = 0; j < 4; j++) {
            const float* wr = wb + (size_t)(kk * 4 + j) * OUTF;
#pragma unroll
            for (int c = 0; c < 20; c++) acc[c] += av[j] * wr[c];
        }
    }
    const float* bp = bout + half * 20;
#pragma unroll
    for (int c = 0; c < 20; c++) acc[c] += bp[c];
    float mx = acc[0];
#pragma unroll
    for (int c = 1; c < 20; c++) mx = fmaxf(mx, acc[c]);
    red_mx[wv][lane] = mx;
    __syncthreads();
    float gmx = fmaxf(mx, red_mx[wv ^ 1][lane]);
    float s = 0.0f;
#pragma unroll
    for (int c = 0; c < 20; c++) s += expf(acc[c] - gmx);
    red_s[wv][lane] = s;
    __syncthreads();
    float lse = logf(s + red_s[wv ^ 1][lane]) + gmx;
    if (node < NN) {
        float4* op = (float4*)(out + (size_t)node * OUTF + half * 20);
#pragma unroll
        for (int q = 0; q < 5; q++) {
            float4 v;
            v.x = acc[q * 4 + 0] - lse;
            v.y = acc[q * 4 + 1] - lse;
            v.z = acc[q * 4 + 2] - lse;
            v.w = acc[q * 4 + 3] - lse;
            op[q] = v;
        }
    }
}

extern "C" void kernel_launch(void* const* d_in, const int* in_sizes, int n_in,
                              void* d_out, int out_size, void* d_ws, size_t ws_size,
                              hipStream_t stream) {
    const float* feat = (const float*)d_in[0];
    const float* Win  = (const float*)d_in[1];
    const float* bin  = (const float*)d_in[2];
    const float* W1   = (const float*)d_in[3];
    const float* W2   = (const float*)d_in[4];
    const float* bvec = (const float*)d_in[5];
    const float* Wout = (const float*)d_in[6];
    const float* bout = (const float*)d_in[7];
    const int*   src  = (const int*)d_in[8];
    const int*   dst  = (const int*)d_in[9];
    float* out = (float*)d_out;

    char* ws = (char*)d_ws;
    size_t off = 0;
    auto take = [&](size_t bytes) {
        void* p = ws + off;
        off += (bytes + 255) & ~(size_t)255;
        return p;
    };
    int* bsum      = (int*)take(512 * 4);
    int* row_start = (int*)take(NN * 4);
    int* col       = (int*)take(NE * 4);
    float* nsrc    = (float*)take(NN * 4);
    float* ndst    = (float*)take(NN * 4);
    int* cnt2      = (int*)take(2 * SLEN * 4);   // [cntD | cntS]
    int* off2      = (int*)take(2 * SLEN * 4);   // [offD | offS]
    int* sincl     = (int*)take(2 * SLEN * 4);
    unsigned short* wcat  = (unsigned short*)take((size_t)NL * 4 * 4 * 64 * 8 * 2);  // 256 KB bf16 frags
    unsigned short* wfrag = (unsigned short*)take((size_t)INF * HID * 2);
    unsigned int* f0b = (unsigned int*)take((size_t)NN * HID * 2);  // bf16
    float* hbuf    = (float*)take((size_t)NN * HID * 4);            // gemm0 partial p0; edst alias; h
    float* part1   = (float*)take((size_t)NN * HID * 4);            // gemm0 partial p1; esrc alias
    unsigned int* hsA = (unsigned int*)take((size_t)NN * HID * 2);  // bf16
    unsigned int* hsB = (unsigned int*)take((size_t)NN * HID * 2);  // bf16

    // setup-phase aliases (dead before k_gemm0 writes them)
    uint2* edst = (uint2*)hbuf;   // NE * 8B = 6.4 MB <= 12.8 MB
    int* esrc   = (int*)part1;    // NE * 4B = 3.2 MB
    int* offD = off2;
    int* offS = off2 + SLEN;

    const int NB_W = (NN + 63) / 64;     // 782
    const int NB_L = (NN + TN - 1) / TN; // 3125 (exact)
    const int NB_O = (NN + 127) / 128;   // 391
    const int NB_S2 = 2 * SLEN / 256;    // 392

    // bucketed CSR build (zero global atomics), single concatenated scan chain
    k_cnt<<<NBLK, 256, 0, stream>>>(src, dst, cnt2);
    gscanA<<<NB_S2, 256, 0, stream>>>(cnt2, sincl, bsum, 2 * SLEN);
    gscanB<<<1, 512, 0, stream>>>(bsum, NB_S2);
    gscanC<<<NB_S2, 256, 0, stream>>>(sincl, cnt2, bsum, off2, 2 * SLEN);
    k_scat<<<NBLK, 256, 0, stream>>>(src, dst, offD, offS, edst, esrc);
    k_build<<<2 * NBUK, 256, 0, stream>>>(edst, esrc, offD, offS, ndst, row_start, col, nsrc);

    k_wpp<<<(NL * 4 * 4 * 64 * 8 + INF * HID + 255) / 256, 256, 0, stream>>>(W1, W2, Win, wcat, wfrag);
    k_gemm0<<<2 * NB_W, 256, 0, stream>>>(feat, wfrag, hbuf, part1);
    k_gfin<<<(NN * 16 + 255) / 256, 256, 0, stream>>>(hbuf, part1, bin, nsrc, hsA, f0b);

    // ping-pong bf16 hs buffers (gathers read arbitrary rows; in-place would race)
    for (int l = 0; l < NL; ++l) {
        const unsigned int* hin = (l & 1) ? hsB : hsA;
        unsigned int* hout = (l & 1) ? hsA : hsB;
        float beta = logf(0.5f / (float)(l + 1) + 1.0f);
        float omb = 1.0f - beta;
        k_layer<<<NB_L, 256, 0, stream>>>(hin, col, row_start, ndst, f0b,
                                          wcat + (size_t)l * 4 * 4 * 64 * 8, bvec + l * HID,
                                          nsrc, omb, hbuf, hout, (l == NL - 1) ? 1 : 0);
    }
    k_out<<<NB_O, 256, 0, stream>>>(hbuf, Wout, bout, out);
}